// Round 1
// baseline (2225.175 us; speedup 1.0000x reference)
//
#include <hip/hip_runtime.h>
#include <math.h>
#include <cstddef>

#define N_NODES 32768
#define C_DIM   128
#define E_EDGES 262144
#define B_GR    64
#define NPG     512
#define WALK_D  20
#define L_LAYERS 4

static constexpr int NF = N_NODES * C_DIM;  // 4,194,304 floats per [N,C] tensor

// ---------------- PE batch-norm statistics ----------------
__global__ __launch_bounds__(256) void pe_stats_k(const float* __restrict__ pe, float* __restrict__ acc)
{
    __shared__ float s[WALK_D], q[WALK_D];
    int tid = threadIdx.x;
    if (tid < WALK_D) { s[tid] = 0.f; q[tid] = 0.f; }
    __syncthreads();
    int i = blockIdx.x * 256 + tid;
    #pragma unroll
    for (int c = 0; c < WALK_D; ++c) {
        float v = pe[i * WALK_D + c];
        atomicAdd(&s[c], v);
        atomicAdd(&q[c], v * v);
    }
    __syncthreads();
    if (tid < WALK_D) {
        atomicAdd(&acc[tid], s[tid]);
        atomicAdd(&acc[32 + tid], q[tid]);
    }
}

__global__ void pe_fin_k(const float* __restrict__ acc, const float* __restrict__ g,
                         const float* __restrict__ b, float* __restrict__ sf)
{
    int c = threadIdx.x;
    if (c >= WALK_D) return;
    float mean = acc[c] * (1.f / N_NODES);
    float var  = acc[32 + c] * (1.f / N_NODES) - mean * mean;
    float sc   = g[c] * rsqrtf(var + 1e-5f);
    sf[c] = sc;
    sf[32 + c] = b[c] - mean * sc;
}

// ---------------- initial embedding h0 = [node_emb[x], BN(pe) @ pe_lin] ----------------
__global__ __launch_bounds__(256) void h0_k(const int* __restrict__ x, const float* __restrict__ pe,
    const float* __restrict__ node_emb, const float* __restrict__ plw, const float* __restrict__ plb,
    const float* __restrict__ pesf, float* __restrict__ h)
{
    int tid = threadIdx.x;
    int i = blockIdx.x * 2 + (tid >> 7);
    int c = tid & 127;
    float v;
    if (c < 120) {
        v = node_emb[x[i] * 120 + c];
    } else {
        int pc = c - 120;
        v = plb[pc];
        #pragma unroll
        for (int k = 0; k < WALK_D; ++k) {
            float pn = pe[i * WALK_D + k] * pesf[k] + pesf[32 + k];
            v = fmaf(pn, plw[k * 8 + pc], v);
        }
    }
    h[i * C_DIM + c] = v;
}

// ---------------- CSR build (by destination) ----------------
__global__ __launch_bounds__(256) void hist_k(const int* __restrict__ dst, int* __restrict__ cnt)
{
    int e = blockIdx.x * 256 + threadIdx.x;
    atomicAdd(&cnt[dst[e]], 1);
}

__global__ __launch_bounds__(1024) void scan_k(const int* __restrict__ cnt, int* __restrict__ indptr)
{
    __shared__ int s[1024];
    int tid = threadIdx.x;
    int carry = 0;
    for (int ch = 0; ch < N_NODES / 1024; ++ch) {
        int idx = ch * 1024 + tid;
        int v = cnt[idx];
        s[tid] = v;
        __syncthreads();
        for (int off = 1; off < 1024; off <<= 1) {
            int t = (tid >= off) ? s[tid - off] : 0;
            __syncthreads();
            if (tid >= off) s[tid] += t;
            __syncthreads();
        }
        indptr[idx] = carry + s[tid] - v;
        carry += s[1023];
        __syncthreads();
    }
    if (tid == 0) indptr[N_NODES] = carry;
}

__global__ __launch_bounds__(256) void scatter_k(const int* __restrict__ dst, const int* __restrict__ indptr,
                                                 int* __restrict__ cur, int* __restrict__ eid)
{
    int e = blockIdx.x * 256 + threadIdx.x;
    int d = dst[e];
    int pos = atomicAdd(&cur[d], 1);
    eid[indptr[d] + pos] = e;
}

// ---------------- GINE message aggregation: z = h + sum_in relu(h[src]+ee[attr]) ----------------
__global__ __launch_bounds__(256) void gine_gather_k(const float* __restrict__ h,
    const int* __restrict__ src, const int* __restrict__ attr,
    const int* __restrict__ indptr, const int* __restrict__ eid,
    const float* __restrict__ edge_emb, float* __restrict__ z)
{
    __shared__ float ee[4 * C_DIM];
    int tid = threadIdx.x;
    ee[tid] = edge_emb[tid];
    ee[tid + 256] = edge_emb[tid + 256];
    __syncthreads();
    int i = blockIdx.x * 2 + (tid >> 7);
    int c = tid & 127;
    int p0 = indptr[i], p1 = indptr[i + 1];
    float sum = 0.f;
    for (int p = p0; p < p1; ++p) {
        int e  = eid[p];
        int sv = src[e];
        int av = attr[e];
        float mv = h[sv * C_DIM + c] + ee[av * C_DIM + c];
        sum += fmaxf(mv, 0.f);
    }
    z[i * C_DIM + c] = sum + h[i * C_DIM + c];
}

// ---------------- generic f32 GEMM: C = op(A) @ B (+bias, +residual, relu, BN stats) ----------------
// AMODE: 0 plain A; 1 A=aff1(A)+aff2(A2) (per-k channel affine, K==128)
// RESMODE: 0 none; 1 +R1; 2 +aff1(R1)+aff2(R2) (per-col affine, NC==128)
template<int KD, int NC, int AMODE, int RESMODE, bool BIAS, bool RELU, bool STATS>
__global__ __launch_bounds__(256) void gemm_k(
    const float* __restrict__ A, const float* __restrict__ A2,
    const float* __restrict__ affA1, const float* __restrict__ affA2,
    const float* __restrict__ Bw, const float* __restrict__ bias,
    const float* R1, const float* R2,
    const float* __restrict__ affR1, const float* __restrict__ affR2,
    float* Cout, float* __restrict__ stats)
{
    __shared__ float As[8][72];
    __shared__ float Bs[8][72];
    __shared__ float cs[64], cq[64];
    const int tid = threadIdx.x;
    const int tx = tid & 15, ty = tid >> 4;
    const int row0 = blockIdx.y * 64;
    const int col0 = blockIdx.x * 64;
    float acc[4][4] = {};
    for (int kt = 0; kt < KD / 8; ++kt) {
        #pragma unroll
        for (int r = 0; r < 2; ++r) {
            int idx = tid + r * 256;
            int m = idx >> 3, k = idx & 7;
            int gk = kt * 8 + k;
            float v = A[(row0 + m) * KD + gk];
            if (AMODE == 1) {
                float v2 = A2[(row0 + m) * KD + gk];
                v = v * affA1[gk] + affA1[128 + gk] + v2 * affA2[gk] + affA2[128 + gk];
            }
            As[k][m] = v;
            int kr = idx >> 6, n = idx & 63;
            Bs[kr][n] = Bw[(kt * 8 + kr) * NC + col0 + n];
        }
        __syncthreads();
        #pragma unroll
        for (int k = 0; k < 8; ++k) {
            float4 av = *(const float4*)&As[k][ty * 4];
            float4 bv = *(const float4*)&Bs[k][tx * 4];
            float aa[4] = {av.x, av.y, av.z, av.w};
            float bb[4] = {bv.x, bv.y, bv.z, bv.w};
            #pragma unroll
            for (int i = 0; i < 4; ++i)
                #pragma unroll
                for (int j = 0; j < 4; ++j)
                    acc[i][j] = fmaf(aa[i], bb[j], acc[i][j]);
        }
        __syncthreads();
    }
    float bcol[4] = {0.f, 0.f, 0.f, 0.f};
    if (BIAS) {
        float4 bv = *(const float4*)&bias[col0 + tx * 4];
        bcol[0] = bv.x; bcol[1] = bv.y; bcol[2] = bv.z; bcol[3] = bv.w;
    }
    float rs1[4], ro1[4], rs2[4], ro2[4];
    if (RESMODE == 2) {
        float4 a = *(const float4*)&affR1[col0 + tx * 4];
        float4 b = *(const float4*)&affR1[128 + col0 + tx * 4];
        float4 c = *(const float4*)&affR2[col0 + tx * 4];
        float4 d = *(const float4*)&affR2[128 + col0 + tx * 4];
        rs1[0]=a.x; rs1[1]=a.y; rs1[2]=a.z; rs1[3]=a.w;
        ro1[0]=b.x; ro1[1]=b.y; ro1[2]=b.z; ro1[3]=b.w;
        rs2[0]=c.x; rs2[1]=c.y; rs2[2]=c.z; rs2[3]=c.w;
        ro2[0]=d.x; ro2[1]=d.y; ro2[2]=d.z; ro2[3]=d.w;
    }
    float colS[4] = {}, colQ[4] = {};
    #pragma unroll
    for (int i = 0; i < 4; ++i) {
        int grow = row0 + ty * 4 + i;
        float vals[4];
        #pragma unroll
        for (int j = 0; j < 4; ++j) vals[j] = acc[i][j] + bcol[j];
        if (RESMODE == 1) {
            float4 rv = *(const float4*)&R1[grow * NC + col0 + tx * 4];
            vals[0] += rv.x; vals[1] += rv.y; vals[2] += rv.z; vals[3] += rv.w;
        }
        if (RESMODE == 2) {
            float4 r1 = *(const float4*)&R1[grow * 128 + col0 + tx * 4];
            float4 r2 = *(const float4*)&R2[grow * 128 + col0 + tx * 4];
            float rr1[4] = {r1.x, r1.y, r1.z, r1.w};
            float rr2[4] = {r2.x, r2.y, r2.z, r2.w};
            #pragma unroll
            for (int j = 0; j < 4; ++j)
                vals[j] += rr1[j] * rs1[j] + ro1[j] + rr2[j] * rs2[j] + ro2[j];
        }
        if (RELU) {
            #pragma unroll
            for (int j = 0; j < 4; ++j) vals[j] = fmaxf(vals[j], 0.f);
        }
        float4 outv = {vals[0], vals[1], vals[2], vals[3]};
        *(float4*)&Cout[grow * NC + col0 + tx * 4] = outv;
        if (STATS) {
            #pragma unroll
            for (int j = 0; j < 4; ++j) { colS[j] += vals[j]; colQ[j] += vals[j] * vals[j]; }
        }
    }
    if (STATS) {
        if (tid < 64) { cs[tid] = 0.f; cq[tid] = 0.f; }
        __syncthreads();
        #pragma unroll
        for (int j = 0; j < 4; ++j) {
            atomicAdd(&cs[tx * 4 + j], colS[j]);
            atomicAdd(&cq[tx * 4 + j], colQ[j]);
        }
        __syncthreads();
        if (tid < 64) {
            atomicAdd(&stats[col0 + tid], cs[tid]);
            atomicAdd(&stats[128 + col0 + tid], cq[tid]);
        }
    }
}

// ---------------- flash-style f32 attention per (q-tile, head, graph) ----------------
__global__ __launch_bounds__(256) void attn_k(const float* __restrict__ qkv, float* __restrict__ ao)
{
    __shared__ float Qs[64][36];
    __shared__ float Kt[32][68];   // transposed: Kt[d][k-row]
    __shared__ float Vs[64][36];
    __shared__ float Ps[64][68];
    const int tid = threadIdx.x;
    const int tx = tid & 15, ty = tid >> 4;
    const int q0 = blockIdx.x * 64;
    const int hd = blockIdx.y;
    const int base = blockIdx.z * NPG;
    const float scale = 0.17677669529663687f;  // 1/sqrt(32)

    #pragma unroll
    for (int r8 = 0; r8 < 8; ++r8) {
        int idx = r8 * 256 + tid;
        int r = idx >> 5, d = idx & 31;
        Qs[r][d] = qkv[(size_t)(base + q0 + r) * 384 + hd * 32 + d];
    }
    float m[4], l[4], o0[4], o1[4];
    #pragma unroll
    for (int i = 0; i < 4; ++i) { m[i] = -1e30f; l[i] = 0.f; o0[i] = 0.f; o1[i] = 0.f; }
    __syncthreads();

    for (int kc = 0; kc < 8; ++kc) {
        #pragma unroll
        for (int r8 = 0; r8 < 8; ++r8) {
            int idx = r8 * 256 + tid;
            int r = idx >> 5, d = idx & 31;
            const float* rowp = &qkv[(size_t)(base + kc * 64 + r) * 384 + hd * 32 + d];
            Kt[d][r] = rowp[128];
            Vs[r][d] = rowp[256];
        }
        __syncthreads();
        float s[4][4] = {};
        #pragma unroll
        for (int d4 = 0; d4 < 8; ++d4) {
            float a[4][4], bb[4][4];
            #pragma unroll
            for (int i = 0; i < 4; ++i) {
                float4 t = *(const float4*)&Qs[ty * 4 + i][d4 * 4];
                a[i][0]=t.x; a[i][1]=t.y; a[i][2]=t.z; a[i][3]=t.w;
            }
            #pragma unroll
            for (int dd = 0; dd < 4; ++dd) {
                float4 t = *(const float4*)&Kt[d4 * 4 + dd][tx * 4];
                bb[dd][0]=t.x; bb[dd][1]=t.y; bb[dd][2]=t.z; bb[dd][3]=t.w;
            }
            #pragma unroll
            for (int i = 0; i < 4; ++i)
                #pragma unroll
                for (int dd = 0; dd < 4; ++dd)
                    #pragma unroll
                    for (int j = 0; j < 4; ++j)
                        s[i][j] = fmaf(a[i][dd], bb[dd][j], s[i][j]);
        }
        #pragma unroll
        for (int i = 0; i < 4; ++i) {
            float sv[4];
            #pragma unroll
            for (int j = 0; j < 4; ++j) sv[j] = s[i][j] * scale;
            float rm = fmaxf(fmaxf(sv[0], sv[1]), fmaxf(sv[2], sv[3]));
            #pragma unroll
            for (int msk = 1; msk < 16; msk <<= 1) rm = fmaxf(rm, __shfl_xor(rm, msk));
            float mn = fmaxf(m[i], rm);
            float alpha = __expf(m[i] - mn);
            float p[4], ps = 0.f;
            #pragma unroll
            for (int j = 0; j < 4; ++j) { p[j] = __expf(sv[j] - mn); ps += p[j]; }
            #pragma unroll
            for (int msk = 1; msk < 16; msk <<= 1) ps += __shfl_xor(ps, msk);
            l[i] = l[i] * alpha + ps;
            m[i] = mn;
            o0[i] *= alpha; o1[i] *= alpha;
            float4 pv = {p[0], p[1], p[2], p[3]};
            *(float4*)&Ps[ty * 4 + i][tx * 4] = pv;
        }
        __syncthreads();
        #pragma unroll
        for (int k4 = 0; k4 < 16; ++k4) {
            float pa[4][4];
            #pragma unroll
            for (int i = 0; i < 4; ++i) {
                float4 t = *(const float4*)&Ps[ty * 4 + i][k4 * 4];
                pa[i][0]=t.x; pa[i][1]=t.y; pa[i][2]=t.z; pa[i][3]=t.w;
            }
            #pragma unroll
            for (int kk = 0; kk < 4; ++kk) {
                float2 vv = *(const float2*)&Vs[k4 * 4 + kk][tx * 2];
                #pragma unroll
                for (int i = 0; i < 4; ++i) {
                    o0[i] = fmaf(pa[i][kk], vv.x, o0[i]);
                    o1[i] = fmaf(pa[i][kk], vv.y, o1[i]);
                }
            }
        }
        __syncthreads();
    }
    #pragma unroll
    for (int i = 0; i < 4; ++i) {
        int n = base + q0 + ty * 4 + i;
        float inv = 1.f / l[i];
        float2 ov = {o0[i] * inv, o1[i] * inv};
        *(float2*)&ao[(size_t)n * 128 + hd * 32 + tx * 2] = ov;
    }
}

// ---------------- BN finalize (up to 2 norms per launch) ----------------
__global__ void bn_fin_k(const float* acc1, const float* g1, const float* b1, float* sf1,
                         const float* acc2, const float* g2, const float* b2, float* sf2)
{
    const float* acc = (blockIdx.x == 0) ? acc1 : acc2;
    const float* g   = (blockIdx.x == 0) ? g1 : g2;
    const float* b   = (blockIdx.x == 0) ? b1 : b2;
    float*       sf  = (blockIdx.x == 0) ? sf1 : sf2;
    if (acc == nullptr) return;
    int c = threadIdx.x;
    float mean = acc[c] * (1.f / N_NODES);
    float var  = acc[128 + c] * (1.f / N_NODES) - mean * mean;
    float sc   = g[c] * rsqrtf(var + 1e-5f);
    sf[c] = sc;
    sf[128 + c] = b[c] - mean * sc;
}

// ---------------- h = scale*t + shift (BN3 apply) ----------------
__global__ __launch_bounds__(256) void bn_apply_k(const float* __restrict__ t, const float* __restrict__ sf,
                                                  float* __restrict__ h)
{
    int idx = blockIdx.x * 256 + threadIdx.x;
    int cg = (idx & 31) * 4;
    float4 v  = *(const float4*)&t[idx * 4];
    float4 sc = *(const float4*)&sf[cg];
    float4 sh = *(const float4*)&sf[128 + cg];
    float4 o;
    o.x = v.x * sc.x + sh.x;
    o.y = v.y * sc.y + sh.y;
    o.z = v.z * sc.z + sh.z;
    o.w = v.w * sc.w + sh.w;
    *(float4*)&h[idx * 4] = o;
}

// ---------------- global add pool ----------------
__global__ __launch_bounds__(128) void pool_k(const float* __restrict__ h, float* __restrict__ g)
{
    int b = blockIdx.x, c = threadIdx.x;
    float s = 0.f;
    for (int i = 0; i < NPG; ++i) s += h[(size_t)((b << 9) + i) * C_DIM + c];
    g[b * C_DIM + c] = s;
}

// ---------------- head MLP: [64,128]->64->32->1 ----------------
__global__ __launch_bounds__(256) void head_mlp_k(const float* __restrict__ g,
    const float* __restrict__ w1, const float* __restrict__ b1,
    const float* __restrict__ w2, const float* __restrict__ b2,
    const float* __restrict__ w3, const float* __restrict__ b3,
    float* __restrict__ out)
{
    __shared__ float gs[64 * 128];
    __shared__ float y1[64 * 64];
    __shared__ float y2[64 * 32];
    int tid = threadIdx.x;
    for (int r = 0; r < 32; ++r) gs[r * 256 + tid] = g[r * 256 + tid];
    __syncthreads();
    for (int t = 0; t < 16; ++t) {
        int idx = t * 256 + tid;
        int gi = idx >> 6, c = idx & 63;
        float s = b1[c];
        for (int k = 0; k < 128; ++k) s = fmaf(gs[gi * 128 + k], w1[k * 64 + c], s);
        y1[gi * 64 + c] = fmaxf(s, 0.f);
    }
    __syncthreads();
    for (int t = 0; t < 8; ++t) {
        int idx = t * 256 + tid;
        int gi = idx >> 5, c = idx & 31;
        float s = b2[c];
        for (int k = 0; k < 64; ++k) s = fmaf(y1[gi * 64 + k], w2[k * 32 + c], s);
        y2[gi * 32 + c] = fmaxf(s, 0.f);
    }
    __syncthreads();
    if (tid < 64) {
        float s = b3[0];
        for (int k = 0; k < 32; ++k) s = fmaf(y2[tid * 32 + k], w3[k], s);
        out[tid] = s;
    }
}

extern "C" void kernel_launch(void* const* d_in, const int* in_sizes, int n_in,
                              void* d_out, int out_size, void* d_ws, size_t ws_size,
                              hipStream_t stream)
{
    const int*   x        = (const int*)  d_in[0];
    const float* pe       = (const float*)d_in[1];
    const int*   ei       = (const int*)  d_in[2];
    const int*   eattr    = (const int*)  d_in[3];
    const float* node_emb = (const float*)d_in[5];
    const float* plw      = (const float*)d_in[6];
    const float* plb      = (const float*)d_in[7];
    const float* pe_g     = (const float*)d_in[8];
    const float* pe_b     = (const float*)d_in[9];
    const float* edge_emb = (const float*)d_in[10];
    const float* gw1      = (const float*)d_in[11];
    const float* gb1      = (const float*)d_in[12];
    const float* gw2      = (const float*)d_in[13];
    const float* gb2      = (const float*)d_in[14];
    const float* wqkv     = (const float*)d_in[15];
    const float* bqkv     = (const float*)d_in[16];
    const float* wo       = (const float*)d_in[17];
    const float* bo       = (const float*)d_in[18];
    const float* n1g      = (const float*)d_in[19];
    const float* n1b      = (const float*)d_in[20];
    const float* n2g      = (const float*)d_in[21];
    const float* n2b      = (const float*)d_in[22];
    const float* n3g      = (const float*)d_in[23];
    const float* n3b      = (const float*)d_in[24];
    const float* fw1      = (const float*)d_in[25];
    const float* fb1      = (const float*)d_in[26];
    const float* fw2      = (const float*)d_in[27];
    const float* fb2      = (const float*)d_in[28];
    const float* mw1      = (const float*)d_in[29];
    const float* mb1      = (const float*)d_in[30];
    const float* mw2      = (const float*)d_in[31];
    const float* mb2      = (const float*)d_in[32];
    const float* mw3      = (const float*)d_in[33];
    const float* mb3      = (const float*)d_in[34];

    float* wf  = (float*)d_ws;
    float* Hb  = wf;                       // h       [N,C]
    float* Zb  = wf + (size_t)NF;          // z / attention-out (aliased)
    float* T1  = wf + 2 * (size_t)NF;      // t1 / t3 (in-place)
    float* QKV = wf + 3 * (size_t)NF;      // qkv [N,384]; t2 and ffn-y1 alias inside after attention
    float* T2  = QKV;
    float* Y1  = wf + 4 * (size_t)NF;      // gine hidden [N,128] / ffn hidden [N,256]
    int* wi     = (int*)(wf + 6 * (size_t)NF);
    int* indptr = wi;                      // N+1
    int* cnt    = wi + 32800;
    int* cnt2   = cnt + N_NODES;
    int* eid    = cnt2 + N_NODES;
    float* st    = (float*)(eid + E_EDGES);
    float* peacc = st;                     // 64
    float* bnacc = st + 64;                // 12*256
    float* pesf  = st + 64 + 12 * 256;     // 64
    float* bnsf  = pesf + 64;              // 12*256
    float* gpool = bnsf + 12 * 256;        // 64*128

    const int* srcA = ei;
    const int* dstA = ei + E_EDGES;

    hipMemsetAsync(peacc, 0, (64 + 12 * 256) * sizeof(float), stream);
    hipMemsetAsync(cnt, 0, 2 * N_NODES * sizeof(int), stream);

    pe_stats_k<<<N_NODES / 256, 256, 0, stream>>>(pe, peacc);
    pe_fin_k<<<1, 32, 0, stream>>>(peacc, pe_g, pe_b, pesf);
    h0_k<<<N_NODES / 2, 256, 0, stream>>>(x, pe, node_emb, plw, plb, pesf, Hb);
    hist_k<<<E_EDGES / 256, 256, 0, stream>>>(dstA, cnt);
    scan_k<<<1, 1024, 0, stream>>>(cnt, indptr);
    scatter_k<<<E_EDGES / 256, 256, 0, stream>>>(dstA, indptr, cnt2, eid);

    for (int l = 0; l < L_LAYERS; ++l) {
        const float* lgw1  = gw1 + (size_t)l * 128 * 128;
        const float* lgb1  = gb1 + (size_t)l * 128;
        const float* lgw2  = gw2 + (size_t)l * 128 * 128;
        const float* lgb2  = gb2 + (size_t)l * 128;
        const float* lwqkv = wqkv + (size_t)l * 128 * 384;
        const float* lbqkv = bqkv + (size_t)l * 384;
        const float* lwo   = wo + (size_t)l * 128 * 128;
        const float* lbo   = bo + (size_t)l * 128;
        const float* lfw1  = fw1 + (size_t)l * 128 * 256;
        const float* lfb1  = fb1 + (size_t)l * 256;
        const float* lfw2  = fw2 + (size_t)l * 256 * 128;
        const float* lfb2  = fb2 + (size_t)l * 128;
        float* acc1 = bnacc + (l * 3 + 0) * 256;  float* sf1v = bnsf + (l * 3 + 0) * 256;
        float* acc2 = bnacc + (l * 3 + 1) * 256;  float* sf2v = bnsf + (l * 3 + 1) * 256;
        float* acc3 = bnacc + (l * 3 + 2) * 256;  float* sf3v = bnsf + (l * 3 + 2) * 256;

        gine_gather_k<<<N_NODES / 2, 256, 0, stream>>>(Hb, srcA, eattr, indptr, eid, edge_emb, Zb);
        gemm_k<128, 128, 0, 0, true, true,  false><<<dim3(2, 512), 256, 0, stream>>>(
            Zb, nullptr, nullptr, nullptr, lgw1, lgb1, nullptr, nullptr, nullptr, nullptr, Y1, nullptr);
        gemm_k<128, 128, 0, 1, true, false, true ><<<dim3(2, 512), 256, 0, stream>>>(
            Y1, nullptr, nullptr, nullptr, lgw2, lgb2, Hb, nullptr, nullptr, nullptr, T1, acc1);
        gemm_k<128, 384, 0, 0, true, false, false><<<dim3(6, 512), 256, 0, stream>>>(
            Hb, nullptr, nullptr, nullptr, lwqkv, lbqkv, nullptr, nullptr, nullptr, nullptr, QKV, nullptr);
        attn_k<<<dim3(8, 4, 64), 256, 0, stream>>>(QKV, Zb);
        gemm_k<128, 128, 0, 1, true, false, true ><<<dim3(2, 512), 256, 0, stream>>>(
            Zb, nullptr, nullptr, nullptr, lwo, lbo, Hb, nullptr, nullptr, nullptr, T2, acc2);
        bn_fin_k<<<2, 128, 0, stream>>>(acc1, n1g + l * 128, n1b + l * 128, sf1v,
                                        acc2, n2g + l * 128, n2b + l * 128, sf2v);
        gemm_k<128, 256, 1, 0, true, true,  false><<<dim3(4, 512), 256, 0, stream>>>(
            T1, T2, sf1v, sf2v, lfw1, lfb1, nullptr, nullptr, nullptr, nullptr, Y1, nullptr);
        gemm_k<256, 128, 0, 2, true, false, true ><<<dim3(2, 512), 256, 0, stream>>>(
            Y1, nullptr, nullptr, nullptr, lfw2, lfb2, T1, T2, sf1v, sf2v, T1, acc3);
        bn_fin_k<<<1, 128, 0, stream>>>(acc3, n3g + l * 128, n3b + l * 128, sf3v,
                                        nullptr, nullptr, nullptr, nullptr);
        bn_apply_k<<<NF / 1024, 256, 0, stream>>>(T1, sf3v, Hb);
    }
    pool_k<<<B_GR, 128, 0, stream>>>(Hb, gpool);
    head_mlp_k<<<1, 256, 0, stream>>>(gpool, mw1, mb1, mw2, mb2, mw3, mb3, (float*)d_out);
}

// Round 2
// 1201.471 us; speedup vs baseline: 1.8520x; 1.8520x over previous
//
#include <hip/hip_runtime.h>
#include <math.h>
#include <cstddef>

#define N_NODES 32768
#define C_DIM   128
#define E_EDGES 262144
#define B_GR    64
#define NPG     512
#define WALK_D  20
#define L_LAYERS 4

static constexpr int NF = N_NODES * C_DIM;  // 4,194,304 floats per [N,C] tensor

typedef __attribute__((ext_vector_type(8))) short bf16x8;
typedef __attribute__((ext_vector_type(4))) float f32x4;
typedef __attribute__((ext_vector_type(4))) short short4v;

__device__ inline unsigned short f2bf(float f)
{
    union { float f; unsigned u; } v; v.f = f;
    unsigned r = v.u + 0x7fff + ((v.u >> 16) & 1);
    return (unsigned short)(r >> 16);
}

// ---------------- PE batch-norm statistics ----------------
__global__ __launch_bounds__(256) void pe_stats_k(const float* __restrict__ pe, float* __restrict__ acc)
{
    __shared__ float s[WALK_D], q[WALK_D];
    int tid = threadIdx.x;
    if (tid < WALK_D) { s[tid] = 0.f; q[tid] = 0.f; }
    __syncthreads();
    int i = blockIdx.x * 256 + tid;
    #pragma unroll
    for (int c = 0; c < WALK_D; ++c) {
        float v = pe[i * WALK_D + c];
        atomicAdd(&s[c], v);
        atomicAdd(&q[c], v * v);
    }
    __syncthreads();
    if (tid < WALK_D) {
        atomicAdd(&acc[tid], s[tid]);
        atomicAdd(&acc[32 + tid], q[tid]);
    }
}

__global__ void pe_fin_k(const float* __restrict__ acc, const float* __restrict__ g,
                         const float* __restrict__ b, float* __restrict__ sf)
{
    int c = threadIdx.x;
    if (c >= WALK_D) return;
    float mean = acc[c] * (1.f / N_NODES);
    float var  = acc[32 + c] * (1.f / N_NODES) - mean * mean;
    float sc   = g[c] * rsqrtf(var + 1e-5f);
    sf[c] = sc;
    sf[32 + c] = b[c] - mean * sc;
}

// ---------------- initial embedding h0 = [node_emb[x], BN(pe) @ pe_lin] ----------------
__global__ __launch_bounds__(256) void h0_k(const int* __restrict__ x, const float* __restrict__ pe,
    const float* __restrict__ node_emb, const float* __restrict__ plw, const float* __restrict__ plb,
    const float* __restrict__ pesf, float* __restrict__ h)
{
    int tid = threadIdx.x;
    int i = blockIdx.x * 2 + (tid >> 7);
    int c = tid & 127;
    float v;
    if (c < 120) {
        v = node_emb[x[i] * 120 + c];
    } else {
        int pc = c - 120;
        v = plb[pc];
        #pragma unroll
        for (int k = 0; k < WALK_D; ++k) {
            float pn = pe[i * WALK_D + k] * pesf[k] + pesf[32 + k];
            v = fmaf(pn, plw[k * 8 + pc], v);
        }
    }
    h[i * C_DIM + c] = v;
}

// ---------------- CSR build (by destination) ----------------
__global__ __launch_bounds__(256) void hist_k(const int* __restrict__ dst, int* __restrict__ cnt)
{
    int e = blockIdx.x * 256 + threadIdx.x;
    atomicAdd(&cnt[dst[e]], 1);
}

__global__ __launch_bounds__(1024) void scan_k(const int* __restrict__ cnt, int* __restrict__ indptr)
{
    __shared__ int s[1024];
    int tid = threadIdx.x;
    int carry = 0;
    for (int ch = 0; ch < N_NODES / 1024; ++ch) {
        int idx = ch * 1024 + tid;
        int v = cnt[idx];
        s[tid] = v;
        __syncthreads();
        for (int off = 1; off < 1024; off <<= 1) {
            int t = (tid >= off) ? s[tid - off] : 0;
            __syncthreads();
            if (tid >= off) s[tid] += t;
            __syncthreads();
        }
        indptr[idx] = carry + s[tid] - v;
        carry += s[1023];
        __syncthreads();
    }
    if (tid == 0) indptr[N_NODES] = carry;
}

__global__ __launch_bounds__(256) void scatter_k(const int* __restrict__ dst, const int* __restrict__ indptr,
                                                 int* __restrict__ cur, int* __restrict__ eid)
{
    int e = blockIdx.x * 256 + threadIdx.x;
    int d = dst[e];
    int pos = atomicAdd(&cur[d], 1);
    eid[indptr[d] + pos] = e;
}

// ---------------- GINE message aggregation: z = h + sum_in relu(h[src]+ee[attr]) ----------------
__global__ __launch_bounds__(256) void gine_gather_k(const float* __restrict__ h,
    const int* __restrict__ src, const int* __restrict__ attr,
    const int* __restrict__ indptr, const int* __restrict__ eid,
    const float* __restrict__ edge_emb, float* __restrict__ z)
{
    __shared__ float ee[4 * C_DIM];
    int tid = threadIdx.x;
    ee[tid] = edge_emb[tid];
    ee[tid + 256] = edge_emb[tid + 256];
    __syncthreads();
    int i = blockIdx.x * 2 + (tid >> 7);
    int c = tid & 127;
    int p0 = indptr[i], p1 = indptr[i + 1];
    float sum = 0.f;
    for (int p = p0; p < p1; ++p) {
        int e  = eid[p];
        int sv = src[e];
        int av = attr[e];
        float mv = h[sv * C_DIM + c] + ee[av * C_DIM + c];
        sum += fmaxf(mv, 0.f);
    }
    z[i * C_DIM + c] = sum + h[i * C_DIM + c];
}

// ---------------- weight prep: W[K][N] f32 -> Wt[N][K] bf16, all 24 matrices ----------------
__global__ __launch_bounds__(256) void wt_prep_k(
    const float* __restrict__ gw1, const float* __restrict__ gw2,
    const float* __restrict__ wqkv, const float* __restrict__ wo,
    const float* __restrict__ fw1, const float* __restrict__ fw2,
    short* __restrict__ out)
{
    __shared__ float ts[32][36];
    int b = blockIdx.x;
    int l = b / 160, t = b % 160;
    const float* src; int K, N; size_t obase; int tile;
    if (t < 16)       { src = gw1  + (size_t)l * 16384; K = 128; N = 128; obase = (size_t)l * 163840 + 0;      tile = t; }
    else if (t < 32)  { src = gw2  + (size_t)l * 16384; K = 128; N = 128; obase = (size_t)l * 163840 + 16384;  tile = t - 16; }
    else if (t < 80)  { src = wqkv + (size_t)l * 49152; K = 128; N = 384; obase = (size_t)l * 163840 + 32768;  tile = t - 32; }
    else if (t < 96)  { src = wo   + (size_t)l * 16384; K = 128; N = 128; obase = (size_t)l * 163840 + 81920;  tile = t - 80; }
    else if (t < 128) { src = fw1  + (size_t)l * 32768; K = 128; N = 256; obase = (size_t)l * 163840 + 98304;  tile = t - 96; }
    else              { src = fw2  + (size_t)l * 32768; K = 256; N = 128; obase = (size_t)l * 163840 + 131072; tile = t - 128; }
    int ntN = N / 32;
    int tk = tile / ntN, tn = tile % ntN;
    int tid = threadIdx.x;
    int r = tid >> 3, c4 = (tid & 7) * 4;
    *(float4*)&ts[r][c4] = *(const float4*)&src[(size_t)(tk * 32 + r) * N + tn * 32 + c4];
    __syncthreads();
    int n = tid >> 3, k4 = (tid & 7) * 4;
    short4v pk;
    #pragma unroll
    for (int i2 = 0; i2 < 4; ++i2) pk[i2] = (short)f2bf(ts[k4 + i2][n]);
    *(short4v*)&out[obase + (size_t)(tn * 32 + n) * K + tk * 32 + k4] = pk;
}

// ---------------- MFMA bf16 GEMM: Cout = op(A) @ Bt^T (+bias,+res,relu,BN-stats) ----------------
// A: [M,KD] f32 (AMODE1: affine-combined A,A2).  Bt: [NC,KD] bf16 (pre-transposed).
// RESMODE: 0 none; 1 +R1; 2 +aff1(R1)+aff2(R2).  STATS: per-col sum/sumsq atomics (NC==128 only).
template<int KD, int NC, int AMODE, int RESMODE, bool RELU, bool STATS, bool OUTBF>
__global__ __launch_bounds__(256) void mgemm_k(
    const float* __restrict__ A, const float* __restrict__ A2,
    const float* __restrict__ affA1, const float* __restrict__ affA2,
    const unsigned short* __restrict__ Bt, const float* __restrict__ bias,
    const float* __restrict__ R1, const float* __restrict__ R2,
    const float* __restrict__ affR1, const float* __restrict__ affR2,
    void* __restrict__ Cout, float* __restrict__ stats)
{
    __shared__ short As[16384];   // [128 rows][128 k] bf16, XOR-swizzled granules
    __shared__ short Bs[16384];   // [128 cols][128 k] bf16
    const int tid = threadIdx.x;
    const int w = tid >> 6;
    const int lane = tid & 63;
    const int lr = lane & 15, lg = lane >> 4;
    const int row0 = blockIdx.y * 128;
    const int col0 = blockIdx.x * 128;

    const f32x4 zero = {0.f, 0.f, 0.f, 0.f};
    f32x4 acc[2][8];
    #pragma unroll
    for (int i = 0; i < 2; ++i)
        #pragma unroll
        for (int cf = 0; cf < 8; ++cf) acc[i][cf] = zero;

    for (int kt = 0; kt < KD / 128; ++kt) {
        if (kt > 0) __syncthreads();
        #pragma unroll
        for (int it = 0; it < 8; ++it) {
            int gid = it * 256 + tid;
            int row = gid >> 4, g = gid & 15;
            const float* ap = &A[(size_t)(row0 + row) * KD + kt * 128 + g * 8];
            float v[8];
            *(float4*)&v[0] = *(const float4*)ap;
            *(float4*)&v[4] = *(const float4*)(ap + 4);
            if (AMODE == 1) {
                const float* ap2 = &A2[(size_t)(row0 + row) * KD + kt * 128 + g * 8];
                float u[8];
                *(float4*)&u[0] = *(const float4*)ap2;
                *(float4*)&u[4] = *(const float4*)(ap2 + 4);
                #pragma unroll
                for (int j = 0; j < 8; ++j) {
                    int ck = g * 8 + j;
                    v[j] = v[j] * affA1[ck] + affA1[128 + ck] + u[j] * affA2[ck] + affA2[128 + ck];
                }
            }
            bf16x8 pk;
            #pragma unroll
            for (int j = 0; j < 8; ++j) pk[j] = (short)f2bf(v[j]);
            *(bf16x8*)&As[(row * 16 + (g ^ (row & 7))) * 8] = pk;
            bf16x8 bv = *(const bf16x8*)&Bt[(size_t)(col0 + row) * KD + kt * 128 + g * 8];
            *(bf16x8*)&Bs[(row * 16 + (g ^ (row & 7))) * 8] = bv;
        }
        __syncthreads();
        #pragma unroll
        for (int ks = 0; ks < 4; ++ks) {
            bf16x8 af[2], bfr[8];
            #pragma unroll
            for (int i = 0; i < 2; ++i) {
                int row = w * 32 + i * 16 + lr;
                int g = ks * 4 + lg;
                af[i] = *(const bf16x8*)&As[(row * 16 + (g ^ (row & 7))) * 8];
            }
            #pragma unroll
            for (int cf = 0; cf < 8; ++cf) {
                int c = cf * 16 + lr;
                int g = ks * 4 + lg;
                bfr[cf] = *(const bf16x8*)&Bs[(c * 16 + (g ^ (c & 7))) * 8];
            }
            #pragma unroll
            for (int i = 0; i < 2; ++i)
                #pragma unroll
                for (int cf = 0; cf < 8; ++cf)
                    acc[i][cf] = __builtin_amdgcn_mfma_f32_16x16x32_bf16(af[i], bfr[cf], acc[i][cf], 0, 0, 0);
        }
    }

    float* cs = (float*)As;       // alias LDS after compute
    float* cq = cs + 128;
    if (STATS) {
        __syncthreads();
        if (tid < 128) { cs[tid] = 0.f; cq[tid] = 0.f; }
        __syncthreads();
    }
    float bs_v[8];
    #pragma unroll
    for (int cf = 0; cf < 8; ++cf) bs_v[cf] = bias[col0 + cf * 16 + lr];
    float rs1[8], ro1[8], rs2[8], ro2[8];
    if (RESMODE == 2) {
        #pragma unroll
        for (int cf = 0; cf < 8; ++cf) {
            int c = cf * 16 + lr;
            rs1[cf] = affR1[c]; ro1[cf] = affR1[128 + c];
            rs2[cf] = affR2[c]; ro2[cf] = affR2[128 + c];
        }
    }
    float colS[8], colQ[8];
    #pragma unroll
    for (int cf = 0; cf < 8; ++cf) { colS[cf] = 0.f; colQ[cf] = 0.f; }
    #pragma unroll
    for (int i = 0; i < 2; ++i) {
        #pragma unroll
        for (int r = 0; r < 4; ++r) {
            size_t grow = row0 + w * 32 + i * 16 + lg * 4 + r;
            #pragma unroll
            for (int cf = 0; cf < 8; ++cf) {
                int c = col0 + cf * 16 + lr;
                float val = acc[i][cf][r] + bs_v[cf];
                if (RESMODE == 1) val += R1[grow * NC + c];
                if (RESMODE == 2) {
                    val += R1[grow * 128 + c] * rs1[cf] + ro1[cf]
                         + R2[grow * 128 + c] * rs2[cf] + ro2[cf];
                }
                if (RELU) val = fmaxf(val, 0.f);
                if (OUTBF) ((unsigned short*)Cout)[grow * NC + c] = f2bf(val);
                else       ((float*)Cout)[grow * NC + c] = val;
                if (STATS) { colS[cf] += val; colQ[cf] += val * val; }
            }
        }
    }
    if (STATS) {
        #pragma unroll
        for (int cf = 0; cf < 8; ++cf) {
            float s = colS[cf], q = colQ[cf];
            s += __shfl_xor(s, 16); s += __shfl_xor(s, 32);
            q += __shfl_xor(q, 16); q += __shfl_xor(q, 32);
            if (lg == 0) { atomicAdd(&cs[cf * 16 + lr], s); atomicAdd(&cq[cf * 16 + lr], q); }
        }
        __syncthreads();
        if (tid < 128) {
            atomicAdd(&stats[tid], cs[tid]);
            atomicAdd(&stats[128 + tid], cq[tid]);
        }
    }
}

// ---------------- MFMA flash attention: per (64-q tile, head, graph) ----------------
__global__ __launch_bounds__(256) void attn_mfma_k(const unsigned short* __restrict__ qkvb,
                                                   float* __restrict__ ao)
{
    __shared__ short Qs[2048];      // [64 q][32 d] swizzled
    __shared__ short Ks[2][2048];   // [64 k][32 d] swizzled, double-buffered
    __shared__ short Vt[2][2048];   // [32 d][64 k] swizzled, double-buffered
    __shared__ short Ps[4][1024];   // per-wave [16 q][64 k]
    const int tid = threadIdx.x;
    const int w = tid >> 6, lane = tid & 63;
    const int lr = lane & 15, lg = lane >> 4;
    const int q0 = blockIdx.x * 64;
    const int hd = blockIdx.y;
    const int base = blockIdx.z * NPG;
    const float SCL = 0.17677669529663687f * 1.44269504089f;  // 1/sqrt(32) * log2(e)

    {
        int row = tid >> 2, g = tid & 3;
        bf16x8 qv = *(const bf16x8*)&qkvb[(size_t)(base + q0 + row) * 384 + hd * 32 + g * 8];
        *(bf16x8*)&Qs[(row * 4 + (g ^ ((row >> 1) & 3))) * 8] = qv;
        const unsigned short* bp = &qkvb[(size_t)(base + row) * 384 + hd * 32 + g * 8];
        *(bf16x8*)&Ks[0][(row * 4 + (g ^ ((row >> 1) & 3))) * 8] = *(const bf16x8*)(bp + 128);
        bf16x8 vv = *(const bf16x8*)(bp + 256);
        #pragma unroll
        for (int j = 0; j < 8; ++j) {
            int d = g * 8 + j;
            Vt[0][d * 64 + (((row >> 3) ^ (d & 7)) << 3) + (row & 7)] = vv[j];
        }
    }
    __syncthreads();
    const int qrow = w * 16 + lr;
    bf16x8 aq = *(const bf16x8*)&Qs[(qrow * 4 + (lg ^ ((qrow >> 1) & 3))) * 8];
    float m[4], lsum[4];
    const f32x4 zero = {0.f, 0.f, 0.f, 0.f};
    f32x4 o[2];
    o[0] = zero; o[1] = zero;
    #pragma unroll
    for (int r = 0; r < 4; ++r) { m[r] = -1e30f; lsum[r] = 0.f; }

    for (int kc = 0; kc < 8; ++kc) {
        int buf = kc & 1;
        if (kc < 7) {
            int row = tid >> 2, g = tid & 3;
            const unsigned short* bp = &qkvb[(size_t)(base + (kc + 1) * 64 + row) * 384 + hd * 32 + g * 8];
            *(bf16x8*)&Ks[buf ^ 1][(row * 4 + (g ^ ((row >> 1) & 3))) * 8] = *(const bf16x8*)(bp + 128);
            bf16x8 vv = *(const bf16x8*)(bp + 256);
            #pragma unroll
            for (int j = 0; j < 8; ++j) {
                int d = g * 8 + j;
                Vt[buf ^ 1][d * 64 + (((row >> 3) ^ (d & 7)) << 3) + (row & 7)] = vv[j];
            }
        }
        f32x4 s[4];
        #pragma unroll
        for (int cf = 0; cf < 4; ++cf) {
            int kr = cf * 16 + lr;
            bf16x8 bk = *(const bf16x8*)&Ks[buf][(kr * 4 + (lg ^ ((kr >> 1) & 3))) * 8];
            s[cf] = __builtin_amdgcn_mfma_f32_16x16x32_bf16(aq, bk, zero, 0, 0, 0);
        }
        #pragma unroll
        for (int r = 0; r < 4; ++r) {
            float v0 = s[0][r] * SCL, v1 = s[1][r] * SCL, v2 = s[2][r] * SCL, v3 = s[3][r] * SCL;
            float rm = fmaxf(fmaxf(v0, v1), fmaxf(v2, v3));
            rm = fmaxf(rm, __shfl_xor(rm, 1));
            rm = fmaxf(rm, __shfl_xor(rm, 2));
            rm = fmaxf(rm, __shfl_xor(rm, 4));
            rm = fmaxf(rm, __shfl_xor(rm, 8));
            float mn = fmaxf(m[r], rm);
            float alpha = exp2f(m[r] - mn);
            float p0 = exp2f(v0 - mn), p1 = exp2f(v1 - mn), p2 = exp2f(v2 - mn), p3 = exp2f(v3 - mn);
            float ps = p0 + p1 + p2 + p3;
            ps += __shfl_xor(ps, 1); ps += __shfl_xor(ps, 2);
            ps += __shfl_xor(ps, 4); ps += __shfl_xor(ps, 8);
            lsum[r] = lsum[r] * alpha + ps;
            m[r] = mn;
            o[0][r] *= alpha; o[1][r] *= alpha;
            int prow = lg * 4 + r;
            int pg = prow * 64;
            Ps[w][pg + ((((lr     ) >> 3) ^ (prow & 7)) << 3) + (lr & 7)] = (short)f2bf(p0);
            Ps[w][pg + ((((lr + 16) >> 3) ^ (prow & 7)) << 3) + (lr & 7)] = (short)f2bf(p1);
            Ps[w][pg + ((((lr + 32) >> 3) ^ (prow & 7)) << 3) + (lr & 7)] = (short)f2bf(p2);
            Ps[w][pg + ((((lr + 48) >> 3) ^ (prow & 7)) << 3) + (lr & 7)] = (short)f2bf(p3);
        }
        bf16x8 pa[2];
        #pragma unroll
        for (int ak = 0; ak < 2; ++ak) {
            int g = ak * 4 + lg;
            pa[ak] = *(const bf16x8*)&Ps[w][(lr * 8 + (g ^ (lr & 7))) * 8];
        }
        #pragma unroll
        for (int of = 0; of < 2; ++of) {
            #pragma unroll
            for (int ak = 0; ak < 2; ++ak) {
                int d = of * 16 + lr;
                int gk = ak * 4 + lg;
                bf16x8 vb = *(const bf16x8*)&Vt[buf][(d * 8 + (gk ^ (d & 7))) * 8];
                o[of] = __builtin_amdgcn_mfma_f32_16x16x32_bf16(pa[ak], vb, o[of], 0, 0, 0);
            }
        }
        __syncthreads();
    }
    #pragma unroll
    for (int r = 0; r < 4; ++r) {
        float inv = 1.f / lsum[r];
        size_t nrow = (size_t)base + q0 + w * 16 + lg * 4 + r;
        ao[nrow * 128 + hd * 32 + lr]      = o[0][r] * inv;
        ao[nrow * 128 + hd * 32 + 16 + lr] = o[1][r] * inv;
    }
}

// ---------------- BN finalize (up to 2 norms per launch) ----------------
__global__ void bn_fin_k(const float* acc1, const float* g1, const float* b1, float* sf1,
                         const float* acc2, const float* g2, const float* b2, float* sf2)
{
    const float* acc = (blockIdx.x == 0) ? acc1 : acc2;
    const float* g   = (blockIdx.x == 0) ? g1 : g2;
    const float* b   = (blockIdx.x == 0) ? b1 : b2;
    float*       sf  = (blockIdx.x == 0) ? sf1 : sf2;
    if (acc == nullptr) return;
    int c = threadIdx.x;
    float mean = acc[c] * (1.f / N_NODES);
    float var  = acc[128 + c] * (1.f / N_NODES) - mean * mean;
    float sc   = g[c] * rsqrtf(var + 1e-5f);
    sf[c] = sc;
    sf[128 + c] = b[c] - mean * sc;
}

// ---------------- h = scale*t + shift (BN3 apply) ----------------
__global__ __launch_bounds__(256) void bn_apply_k(const float* __restrict__ t, const float* __restrict__ sf,
                                                  float* __restrict__ h)
{
    int idx = blockIdx.x * 256 + threadIdx.x;
    int cg = (idx & 31) * 4;
    float4 v  = *(const float4*)&t[idx * 4];
    float4 sc = *(const float4*)&sf[cg];
    float4 sh = *(const float4*)&sf[128 + cg];
    float4 o;
    o.x = v.x * sc.x + sh.x;
    o.y = v.y * sc.y + sh.y;
    o.z = v.z * sc.z + sh.z;
    o.w = v.w * sc.w + sh.w;
    *(float4*)&h[idx * 4] = o;
}

// ---------------- global add pool ----------------
__global__ __launch_bounds__(128) void pool_k(const float* __restrict__ h, float* __restrict__ g)
{
    int b = blockIdx.x, c = threadIdx.x;
    float s = 0.f;
    for (int i = 0; i < NPG; ++i) s += h[(size_t)((b << 9) + i) * C_DIM + c];
    g[b * C_DIM + c] = s;
}

// ---------------- head MLP: [64,128]->64->32->1 ----------------
__global__ __launch_bounds__(256) void head_mlp_k(const float* __restrict__ g,
    const float* __restrict__ w1, const float* __restrict__ b1,
    const float* __restrict__ w2, const float* __restrict__ b2,
    const float* __restrict__ w3, const float* __restrict__ b3,
    float* __restrict__ out)
{
    __shared__ float gs[64 * 128];
    __shared__ float y1[64 * 64];
    __shared__ float y2[64 * 32];
    int tid = threadIdx.x;
    for (int r = 0; r < 32; ++r) gs[r * 256 + tid] = g[r * 256 + tid];
    __syncthreads();
    for (int t = 0; t < 16; ++t) {
        int idx = t * 256 + tid;
        int gi = idx >> 6, c = idx & 63;
        float s = b1[c];
        for (int k = 0; k < 128; ++k) s = fmaf(gs[gi * 128 + k], w1[k * 64 + c], s);
        y1[gi * 64 + c] = fmaxf(s, 0.f);
    }
    __syncthreads();
    for (int t = 0; t < 8; ++t) {
        int idx = t * 256 + tid;
        int gi = idx >> 5, c = idx & 31;
        float s = b2[c];
        for (int k = 0; k < 64; ++k) s = fmaf(y1[gi * 64 + k], w2[k * 32 + c], s);
        y2[gi * 32 + c] = fmaxf(s, 0.f);
    }
    __syncthreads();
    if (tid < 64) {
        float s = b3[0];
        for (int k = 0; k < 32; ++k) s = fmaf(y2[tid * 32 + k], w3[k], s);
        out[tid] = s;
    }
}

extern "C" void kernel_launch(void* const* d_in, const int* in_sizes, int n_in,
                              void* d_out, int out_size, void* d_ws, size_t ws_size,
                              hipStream_t stream)
{
    const int*   x        = (const int*)  d_in[0];
    const float* pe       = (const float*)d_in[1];
    const int*   ei       = (const int*)  d_in[2];
    const int*   eattr    = (const int*)  d_in[3];
    const float* node_emb = (const float*)d_in[5];
    const float* plw      = (const float*)d_in[6];
    const float* plb      = (const float*)d_in[7];
    const float* pe_g     = (const float*)d_in[8];
    const float* pe_b     = (const float*)d_in[9];
    const float* edge_emb = (const float*)d_in[10];
    const float* gw1      = (const float*)d_in[11];
    const float* gb1      = (const float*)d_in[12];
    const float* gw2      = (const float*)d_in[13];
    const float* gb2      = (const float*)d_in[14];
    const float* wqkv     = (const float*)d_in[15];
    const float* bqkv     = (const float*)d_in[16];
    const float* wo       = (const float*)d_in[17];
    const float* bo       = (const float*)d_in[18];
    const float* n1g      = (const float*)d_in[19];
    const float* n1b      = (const float*)d_in[20];
    const float* n2g      = (const float*)d_in[21];
    const float* n2b      = (const float*)d_in[22];
    const float* n3g      = (const float*)d_in[23];
    const float* n3b      = (const float*)d_in[24];
    const float* fw1      = (const float*)d_in[25];
    const float* fb1      = (const float*)d_in[26];
    const float* fw2      = (const float*)d_in[27];
    const float* fb2      = (const float*)d_in[28];
    const float* mw1      = (const float*)d_in[29];
    const float* mb1      = (const float*)d_in[30];
    const float* mw2      = (const float*)d_in[31];
    const float* mb2      = (const float*)d_in[32];
    const float* mw3      = (const float*)d_in[33];
    const float* mb3      = (const float*)d_in[34];

    float* wf  = (float*)d_ws;
    float* Hb  = wf;                       // h  [N,C] f32
    float* Zb  = wf + (size_t)NF;          // z / attention-out (aliased) f32
    float* T1  = wf + 2 * (size_t)NF;      // t1 / t3 (in-place) f32
    unsigned short* QKVb = (unsigned short*)(wf + 3 * (size_t)NF);  // qkv bf16 [N,384] (floats 3NF..4.5NF)
    float* T2  = wf + 3 * (size_t)NF;      // t2 aliases dead qkv low half after attention
    float* Y1  = wf + 4 * (size_t)NF;      // gine hidden [N,128] / ffn hidden [N,256] f32
    int* wi     = (int*)(wf + 6 * (size_t)NF);
    int* indptr = wi;                      // N+1
    int* cnt    = wi + 32800;
    int* cnt2   = cnt + N_NODES;
    int* eid    = cnt2 + N_NODES;
    float* st    = (float*)(eid + E_EDGES);
    float* peacc = st;                     // 64
    float* bnacc = st + 64;                // 12*256
    float* pesf  = st + 64 + 12 * 256;     // 64
    float* bnsf  = pesf + 64;              // 12*256
    float* gpool = bnsf + 12 * 256;        // 64*128
    short* wT    = (short*)(gpool + 64 * 128);  // 655360 bf16 transposed weights

    const int* srcA = ei;
    const int* dstA = ei + E_EDGES;
    const int LSTR = 163840;

    hipMemsetAsync(peacc, 0, (64 + 12 * 256) * sizeof(float), stream);
    hipMemsetAsync(cnt, 0, 2 * N_NODES * sizeof(int), stream);

    wt_prep_k<<<640, 256, 0, stream>>>(gw1, gw2, wqkv, wo, fw1, fw2, wT);
    pe_stats_k<<<N_NODES / 256, 256, 0, stream>>>(pe, peacc);
    pe_fin_k<<<1, 32, 0, stream>>>(peacc, pe_g, pe_b, pesf);
    h0_k<<<N_NODES / 2, 256, 0, stream>>>(x, pe, node_emb, plw, plb, pesf, Hb);
    hist_k<<<E_EDGES / 256, 256, 0, stream>>>(dstA, cnt);
    scan_k<<<1, 1024, 0, stream>>>(cnt, indptr);
    scatter_k<<<E_EDGES / 256, 256, 0, stream>>>(dstA, indptr, cnt2, eid);

    for (int l = 0; l < L_LAYERS; ++l) {
        const short* gw1t  = wT + (size_t)l * LSTR;
        const short* gw2t  = wT + (size_t)l * LSTR + 16384;
        const short* wqkvt = wT + (size_t)l * LSTR + 32768;
        const short* wot   = wT + (size_t)l * LSTR + 81920;
        const short* fw1t  = wT + (size_t)l * LSTR + 98304;
        const short* fw2t  = wT + (size_t)l * LSTR + 131072;
        const float* lgb1  = gb1 + (size_t)l * 128;
        const float* lgb2  = gb2 + (size_t)l * 128;
        const float* lbqkv = bqkv + (size_t)l * 384;
        const float* lbo   = bo + (size_t)l * 128;
        const float* lfb1  = fb1 + (size_t)l * 256;
        const float* lfb2  = fb2 + (size_t)l * 128;
        float* acc1 = bnacc + (l * 3 + 0) * 256;  float* sf1v = bnsf + (l * 3 + 0) * 256;
        float* acc2 = bnacc + (l * 3 + 1) * 256;  float* sf2v = bnsf + (l * 3 + 1) * 256;
        float* acc3 = bnacc + (l * 3 + 2) * 256;  float* sf3v = bnsf + (l * 3 + 2) * 256;

        gine_gather_k<<<N_NODES / 2, 256, 0, stream>>>(Hb, srcA, eattr, indptr, eid, edge_emb, Zb);
        mgemm_k<128, 128, 0, 0, true,  false, false><<<dim3(1, 256), 256, 0, stream>>>(
            Zb, nullptr, nullptr, nullptr, (const unsigned short*)gw1t, lgb1,
            nullptr, nullptr, nullptr, nullptr, Y1, nullptr);
        mgemm_k<128, 128, 0, 1, false, true,  false><<<dim3(1, 256), 256, 0, stream>>>(
            Y1, nullptr, nullptr, nullptr, (const unsigned short*)gw2t, lgb2,
            Hb, nullptr, nullptr, nullptr, T1, acc1);
        mgemm_k<128, 384, 0, 0, false, false, true ><<<dim3(3, 256), 256, 0, stream>>>(
            Hb, nullptr, nullptr, nullptr, (const unsigned short*)wqkvt, lbqkv,
            nullptr, nullptr, nullptr, nullptr, QKVb, nullptr);
        attn_mfma_k<<<dim3(8, 4, 64), 256, 0, stream>>>(QKVb, Zb);
        mgemm_k<128, 128, 0, 1, false, true,  false><<<dim3(1, 256), 256, 0, stream>>>(
            Zb, nullptr, nullptr, nullptr, (const unsigned short*)wot, lbo,
            Hb, nullptr, nullptr, nullptr, T2, acc2);
        bn_fin_k<<<2, 128, 0, stream>>>(acc1, n1g + l * 128, n1b + l * 128, sf1v,
                                        acc2, n2g + l * 128, n2b + l * 128, sf2v);
        mgemm_k<128, 256, 1, 0, true,  false, false><<<dim3(2, 256), 256, 0, stream>>>(
            T1, T2, sf1v, sf2v, (const unsigned short*)fw1t, lfb1,
            nullptr, nullptr, nullptr, nullptr, Y1, nullptr);
        mgemm_k<256, 128, 0, 2, false, true,  false><<<dim3(1, 256), 256, 0, stream>>>(
            Y1, nullptr, nullptr, nullptr, (const unsigned short*)fw2t, lfb2,
            T1, T2, sf1v, sf2v, T1, acc3);
        bn_fin_k<<<1, 128, 0, stream>>>(acc3, n3g + l * 128, n3b + l * 128, sf3v,
                                        nullptr, nullptr, nullptr, nullptr);
        bn_apply_k<<<NF / 1024, 256, 0, stream>>>(T1, sf3v, Hb);
    }
    pool_k<<<B_GR, 128, 0, stream>>>(Hb, gpool);
    head_mlp_k<<<1, 256, 0, stream>>>(gpool, mw1, mb1, mw2, mb2, mw3, mb3, (float*)d_out);
}

// Round 3
// 929.627 us; speedup vs baseline: 2.3936x; 1.2924x over previous
//
#include <hip/hip_runtime.h>
#include <math.h>
#include <cstddef>

#define N_NODES 32768
#define C_DIM   128
#define E_EDGES 262144
#define B_GR    64
#define NPG     512
#define WALK_D  20
#define L_LAYERS 4

static constexpr int NF = N_NODES * C_DIM;  // 4,194,304 floats per [N,C] tensor

typedef __attribute__((ext_vector_type(8))) short bf16x8;
typedef __attribute__((ext_vector_type(4))) float f32x4;
typedef __attribute__((ext_vector_type(4))) short short4v;

__device__ inline unsigned short f2bf(float f)
{
    union { float f; unsigned u; } v; v.f = f;
    unsigned r = v.u + 0x7fff + ((v.u >> 16) & 1);
    return (unsigned short)(r >> 16);
}
__device__ inline float bf2f_lo(unsigned u) { return __uint_as_float(u << 16); }
__device__ inline float bf2f_hi(unsigned u) { return __uint_as_float(u & 0xffff0000u); }

// ---------------- PE batch-norm statistics: register-private + wave reduce ----------------
__global__ __launch_bounds__(256) void pe_stats_k(const float* __restrict__ pe, float* __restrict__ acc)
{
    int gt = blockIdx.x * 256 + threadIdx.x;   // 8192 threads, 4 rows each
    float s[WALK_D], q[WALK_D];
    #pragma unroll
    for (int c = 0; c < WALK_D; ++c) { s[c] = 0.f; q[c] = 0.f; }
    for (int r = 0; r < 4; ++r) {
        const float* row = &pe[(size_t)(gt + r * 8192) * WALK_D];
        float v[20];
        #pragma unroll
        for (int j = 0; j < 5; ++j) *(float4*)&v[j * 4] = *(const float4*)(row + j * 4);
        #pragma unroll
        for (int c = 0; c < WALK_D; ++c) { s[c] += v[c]; q[c] += v[c] * v[c]; }
    }
    #pragma unroll
    for (int c = 0; c < WALK_D; ++c) {
        float ss = s[c], qq = q[c];
        #pragma unroll
        for (int m = 1; m < 64; m <<= 1) { ss += __shfl_xor(ss, m); qq += __shfl_xor(qq, m); }
        if ((threadIdx.x & 63) == 0) { atomicAdd(&acc[c], ss); atomicAdd(&acc[32 + c], qq); }
    }
}

__global__ void pe_fin_k(const float* __restrict__ acc, const float* __restrict__ g,
                         const float* __restrict__ b, float* __restrict__ sf)
{
    int c = threadIdx.x;
    if (c >= WALK_D) return;
    float mean = acc[c] * (1.f / N_NODES);
    float var  = acc[32 + c] * (1.f / N_NODES) - mean * mean;
    float sc   = g[c] * rsqrtf(var + 1e-5f);
    sf[c] = sc;
    sf[32 + c] = b[c] - mean * sc;
}

// ---------------- initial embedding h0 = [node_emb[x], BN(pe) @ pe_lin] ----------------
__global__ __launch_bounds__(256) void h0_k(const int* __restrict__ x, const float* __restrict__ pe,
    const float* __restrict__ node_emb, const float* __restrict__ plw, const float* __restrict__ plb,
    const float* __restrict__ pesf, float* __restrict__ h, unsigned short* __restrict__ h16)
{
    int tid = threadIdx.x;
    int i = blockIdx.x * 2 + (tid >> 7);
    int c = tid & 127;
    float v;
    if (c < 120) {
        v = node_emb[x[i] * 120 + c];
    } else {
        int pc = c - 120;
        v = plb[pc];
        #pragma unroll
        for (int k = 0; k < WALK_D; ++k) {
            float pn = pe[i * WALK_D + k] * pesf[k] + pesf[32 + k];
            v = fmaf(pn, plw[k * 8 + pc], v);
        }
    }
    h[i * C_DIM + c] = v;
    h16[i * C_DIM + c] = f2bf(v);
}

// ---------------- CSR build (by destination) ----------------
__global__ __launch_bounds__(256) void hist_k(const int* __restrict__ dst, int* __restrict__ cnt)
{
    int e = blockIdx.x * 256 + threadIdx.x;
    atomicAdd(&cnt[dst[e]], 1);
}

__global__ __launch_bounds__(256) void bsum_k(const int* __restrict__ cnt, int* __restrict__ bsum)
{
    __shared__ int ws[4];
    int b = blockIdx.x, t = threadIdx.x;
    int v = cnt[b * 256 + t];
    #pragma unroll
    for (int m = 1; m < 64; m <<= 1) v += __shfl_xor(v, m);
    if ((t & 63) == 0) ws[t >> 6] = v;
    __syncthreads();
    if (t == 0) bsum[b] = ws[0] + ws[1] + ws[2] + ws[3];
}

__global__ __launch_bounds__(128) void bscan_k(const int* __restrict__ bsum, int* __restrict__ bpre)
{
    __shared__ int s[128];
    int t = threadIdx.x;
    int v = bsum[t];
    s[t] = v;
    __syncthreads();
    for (int off = 1; off < 128; off <<= 1) {
        int u = (t >= off) ? s[t - off] : 0;
        __syncthreads();
        s[t] += u;
        __syncthreads();
    }
    bpre[t] = s[t] - v;
}

__global__ __launch_bounds__(256) void indptr_k(const int* __restrict__ cnt, const int* __restrict__ bpre,
                                                int* __restrict__ indptr)
{
    __shared__ int s[256];
    int b = blockIdx.x, t = threadIdx.x;
    int v = cnt[b * 256 + t];
    s[t] = v;
    __syncthreads();
    for (int off = 1; off < 256; off <<= 1) {
        int u = (t >= off) ? s[t - off] : 0;
        __syncthreads();
        s[t] += u;
        __syncthreads();
    }
    indptr[b * 256 + t] = bpre[b] + s[t] - v;
    if (b == 127 && t == 255) indptr[N_NODES] = E_EDGES;
}

__global__ __launch_bounds__(256) void scatter_k(const int* __restrict__ dst, const int* __restrict__ indptr,
                                                 int* __restrict__ cur, int* __restrict__ eid)
{
    int e = blockIdx.x * 256 + threadIdx.x;
    int d = dst[e];
    int pos = atomicAdd(&cur[d], 1);
    eid[indptr[d] + pos] = e;
}

// ---------------- GINE message aggregation (bf16 in/out): z = h + sum_in relu(h[src]+ee) ----------------
__global__ __launch_bounds__(256) void gine_gather_k(const unsigned short* __restrict__ h16,
    const int* __restrict__ src, const int* __restrict__ attr,
    const int* __restrict__ indptr, const int* __restrict__ eid,
    const float* __restrict__ edge_emb, unsigned short* __restrict__ z16)
{
    __shared__ float ee[4 * C_DIM];
    int tid = threadIdx.x;
    ee[tid] = edge_emb[tid];
    ee[tid + 256] = edge_emb[tid + 256];
    __syncthreads();
    int i = blockIdx.x * 4 + (tid >> 6);
    int c = (tid & 63) * 2;
    int p0 = indptr[i], p1 = indptr[i + 1];
    float s0 = 0.f, s1 = 0.f;
    for (int p = p0; p < p1; ++p) {
        int e  = eid[p];
        int sv = src[e];
        int av = attr[e];
        unsigned u = *(const unsigned*)&h16[(size_t)sv * C_DIM + c];
        float m0 = bf2f_lo(u) + ee[av * C_DIM + c];
        float m1 = bf2f_hi(u) + ee[av * C_DIM + c + 1];
        s0 += fmaxf(m0, 0.f);
        s1 += fmaxf(m1, 0.f);
    }
    unsigned us = *(const unsigned*)&h16[(size_t)i * C_DIM + c];
    s0 += bf2f_lo(us);
    s1 += bf2f_hi(us);
    unsigned out = (unsigned)f2bf(s0) | ((unsigned)f2bf(s1) << 16);
    *(unsigned*)&z16[(size_t)i * C_DIM + c] = out;
}

// ---------------- weight prep: W[K][N] f32 -> Wt[N][K] bf16, all 24 matrices ----------------
__global__ __launch_bounds__(256) void wt_prep_k(
    const float* __restrict__ gw1, const float* __restrict__ gw2,
    const float* __restrict__ wqkv, const float* __restrict__ wo,
    const float* __restrict__ fw1, const float* __restrict__ fw2,
    short* __restrict__ out)
{
    __shared__ float ts[32][36];
    int b = blockIdx.x;
    int l = b / 160, t = b % 160;
    const float* src; int K, N; size_t obase; int tile;
    if (t < 16)       { src = gw1  + (size_t)l * 16384; K = 128; N = 128; obase = (size_t)l * 163840 + 0;      tile = t; }
    else if (t < 32)  { src = gw2  + (size_t)l * 16384; K = 128; N = 128; obase = (size_t)l * 163840 + 16384;  tile = t - 16; }
    else if (t < 80)  { src = wqkv + (size_t)l * 49152; K = 128; N = 384; obase = (size_t)l * 163840 + 32768;  tile = t - 32; }
    else if (t < 96)  { src = wo   + (size_t)l * 16384; K = 128; N = 128; obase = (size_t)l * 163840 + 81920;  tile = t - 80; }
    else if (t < 128) { src = fw1  + (size_t)l * 32768; K = 128; N = 256; obase = (size_t)l * 163840 + 98304;  tile = t - 96; }
    else              { src = fw2  + (size_t)l * 32768; K = 256; N = 128; obase = (size_t)l * 163840 + 131072; tile = t - 128; }
    int ntN = N / 32;
    int tk = tile / ntN, tn = tile % ntN;
    int tid = threadIdx.x;
    int r = tid >> 3, c4 = (tid & 7) * 4;
    *(float4*)&ts[r][c4] = *(const float4*)&src[(size_t)(tk * 32 + r) * N + tn * 32 + c4];
    __syncthreads();
    int n = tid >> 3, k4 = (tid & 7) * 4;
    short4v pk;
    #pragma unroll
    for (int i2 = 0; i2 < 4; ++i2) pk[i2] = (short)f2bf(ts[k4 + i2][n]);
    *(short4v*)&out[obase + (size_t)(tn * 32 + n) * K + tk * 32 + k4] = pk;
}

// ---------------- MFMA bf16 GEMM: Cout = op(A) @ Bt^T (+bias,+res,relu,BN-stats) ----------------
// Av: [M,KD] f32 (ABF=false) or bf16 (ABF=true). AMODE1 (f32 only): affine-combined A,A2.
// Bt: [NC,KD] bf16.  RESMODE: 0 none; 1 +R1; 2 +aff1(R1)+aff2(R2).  STATS: col sum/sumsq (NC==128).
template<int KD, int NC, int AMODE, int RESMODE, bool RELU, bool STATS, bool OUTBF, bool ABF>
__global__ __launch_bounds__(256) void mgemm_k(
    const void* __restrict__ Av, const float* __restrict__ A2,
    const float* __restrict__ affA1, const float* __restrict__ affA2,
    const unsigned short* __restrict__ Bt, const float* __restrict__ bias,
    const float* __restrict__ R1, const float* __restrict__ R2,
    const float* __restrict__ affR1, const float* __restrict__ affR2,
    void* __restrict__ Cout, float* __restrict__ stats)
{
    __shared__ short As[16384];   // [128 rows][128 k] bf16, XOR-swizzled granules
    __shared__ short Bs[16384];   // [128 cols][128 k] bf16
    const int tid = threadIdx.x;
    const int w = tid >> 6;
    const int lane = tid & 63;
    const int lr = lane & 15, lg = lane >> 4;
    const int row0 = blockIdx.y * 128;
    const int col0 = blockIdx.x * 128;

    const f32x4 zero = {0.f, 0.f, 0.f, 0.f};
    f32x4 acc[2][8];
    #pragma unroll
    for (int i = 0; i < 2; ++i)
        #pragma unroll
        for (int cf = 0; cf < 8; ++cf) acc[i][cf] = zero;

    for (int kt = 0; kt < KD / 128; ++kt) {
        if (kt > 0) __syncthreads();
        #pragma unroll
        for (int it = 0; it < 8; ++it) {
            int gid = it * 256 + tid;
            int row = gid >> 4, g = gid & 15;
            bf16x8 pk;
            if (ABF) {
                pk = *(const bf16x8*)&((const unsigned short*)Av)[(size_t)(row0 + row) * KD + kt * 128 + g * 8];
            } else {
                const float* Af = (const float*)Av;
                const float* ap = &Af[(size_t)(row0 + row) * KD + kt * 128 + g * 8];
                float v[8];
                *(float4*)&v[0] = *(const float4*)ap;
                *(float4*)&v[4] = *(const float4*)(ap + 4);
                if (AMODE == 1) {
                    const float* ap2 = &A2[(size_t)(row0 + row) * KD + kt * 128 + g * 8];
                    float u[8];
                    *(float4*)&u[0] = *(const float4*)ap2;
                    *(float4*)&u[4] = *(const float4*)(ap2 + 4);
                    #pragma unroll
                    for (int j = 0; j < 8; ++j) {
                        int ck = g * 8 + j;
                        v[j] = v[j] * affA1[ck] + affA1[128 + ck] + u[j] * affA2[ck] + affA2[128 + ck];
                    }
                }
                #pragma unroll
                for (int j = 0; j < 8; ++j) pk[j] = (short)f2bf(v[j]);
            }
            *(bf16x8*)&As[(row * 16 + (g ^ (row & 7))) * 8] = pk;
            bf16x8 bv = *(const bf16x8*)&Bt[(size_t)(col0 + row) * KD + kt * 128 + g * 8];
            *(bf16x8*)&Bs[(row * 16 + (g ^ (row & 7))) * 8] = bv;
        }
        __syncthreads();
        #pragma unroll
        for (int ks = 0; ks < 4; ++ks) {
            bf16x8 af[2], bfr[8];
            #pragma unroll
            for (int i = 0; i < 2; ++i) {
                int row = w * 32 + i * 16 + lr;
                int g = ks * 4 + lg;
                af[i] = *(const bf16x8*)&As[(row * 16 + (g ^ (row & 7))) * 8];
            }
            #pragma unroll
            for (int cf = 0; cf < 8; ++cf) {
                int c = cf * 16 + lr;
                int g = ks * 4 + lg;
                bfr[cf] = *(const bf16x8*)&Bs[(c * 16 + (g ^ (c & 7))) * 8];
            }
            #pragma unroll
            for (int i = 0; i < 2; ++i)
                #pragma unroll
                for (int cf = 0; cf < 8; ++cf)
                    acc[i][cf] = __builtin_amdgcn_mfma_f32_16x16x32_bf16(af[i], bfr[cf], acc[i][cf], 0, 0, 0);
        }
    }

    float* cs = (float*)As;       // alias LDS after compute
    float* cq = cs + 128;
    if (STATS) {
        __syncthreads();
        if (tid < 128) { cs[tid] = 0.f; cq[tid] = 0.f; }
        __syncthreads();
    }
    float bs_v[8];
    #pragma unroll
    for (int cf = 0; cf < 8; ++cf) bs_v[cf] = bias[col0 + cf * 16 + lr];
    float rs1[8], ro1[8], rs2[8], ro2[8];
    if (RESMODE == 2) {
        #pragma unroll
        for (int cf = 0; cf < 8; ++cf) {
            int c = cf * 16 + lr;
            rs1[cf] = affR1[c]; ro1[cf] = affR1[128 + c];
            rs2[cf] = affR2[c]; ro2[cf] = affR2[128 + c];
        }
    }
    float colS[8], colQ[8];
    #pragma unroll
    for (int cf = 0; cf < 8; ++cf) { colS[cf] = 0.f; colQ[cf] = 0.f; }
    #pragma unroll
    for (int i = 0; i < 2; ++i) {
        #pragma unroll
        for (int r = 0; r < 4; ++r) {
            size_t grow = row0 + w * 32 + i * 16 + lg * 4 + r;
            #pragma unroll
            for (int cf = 0; cf < 8; ++cf) {
                int c = col0 + cf * 16 + lr;
                float val = acc[i][cf][r] + bs_v[cf];
                if (RESMODE == 1) val += R1[grow * NC + c];
                if (RESMODE == 2) {
                    val += R1[grow * 128 + c] * rs1[cf] + ro1[cf]
                         + R2[grow * 128 + c] * rs2[cf] + ro2[cf];
                }
                if (RELU) val = fmaxf(val, 0.f);
                if (OUTBF) ((unsigned short*)Cout)[grow * NC + c] = f2bf(val);
                else       ((float*)Cout)[grow * NC + c] = val;
                if (STATS) { colS[cf] += val; colQ[cf] += val * val; }
            }
        }
    }
    if (STATS) {
        #pragma unroll
        for (int cf = 0; cf < 8; ++cf) {
            float s = colS[cf], q = colQ[cf];
            s += __shfl_xor(s, 16); s += __shfl_xor(s, 32);
            q += __shfl_xor(q, 16); q += __shfl_xor(q, 32);
            if (lg == 0) { atomicAdd(&cs[cf * 16 + lr], s); atomicAdd(&cq[cf * 16 + lr], q); }
        }
        __syncthreads();
        if (tid < 128) {
            atomicAdd(&stats[tid], cs[tid]);
            atomicAdd(&stats[128 + tid], cq[tid]);
        }
    }
}

// ---------------- MFMA flash attention: per (64-q tile, head, graph), bf16 out ----------------
__global__ __launch_bounds__(256) void attn_mfma_k(const unsigned short* __restrict__ qkvb,
                                                   unsigned short* __restrict__ ao16)
{
    __shared__ short Qs[2048];      // [64 q][32 d] swizzled
    __shared__ short Ks[2][2048];   // [64 k][32 d] swizzled, double-buffered
    __shared__ short Vt[2][2048];   // [32 d][64 k] swizzled, double-buffered
    __shared__ short Ps[4][1024];   // per-wave [16 q][64 k]
    const int tid = threadIdx.x;
    const int w = tid >> 6, lane = tid & 63;
    const int lr = lane & 15, lg = lane >> 4;
    const int q0 = blockIdx.x * 64;
    const int hd = blockIdx.y;
    const int base = blockIdx.z * NPG;
    const float SCL = 0.17677669529663687f * 1.44269504089f;  // 1/sqrt(32) * log2(e)

    {
        int row = tid >> 2, g = tid & 3;
        bf16x8 qv = *(const bf16x8*)&qkvb[(size_t)(base + q0 + row) * 384 + hd * 32 + g * 8];
        *(bf16x8*)&Qs[(row * 4 + (g ^ ((row >> 1) & 3))) * 8] = qv;
        const unsigned short* bp = &qkvb[(size_t)(base + row) * 384 + hd * 32 + g * 8];
        *(bf16x8*)&Ks[0][(row * 4 + (g ^ ((row >> 1) & 3))) * 8] = *(const bf16x8*)(bp + 128);
        bf16x8 vv = *(const bf16x8*)(bp + 256);
        #pragma unroll
        for (int j = 0; j < 8; ++j) {
            int d = g * 8 + j;
            Vt[0][d * 64 + (((row >> 3) ^ (d & 7)) << 3) + (row & 7)] = vv[j];
        }
    }
    __syncthreads();
    const int qrow = w * 16 + lr;
    bf16x8 aq = *(const bf16x8*)&Qs[(qrow * 4 + (lg ^ ((qrow >> 1) & 3))) * 8];
    float m[4], lsum[4];
    const f32x4 zero = {0.f, 0.f, 0.f, 0.f};
    f32x4 o[2];
    o[0] = zero; o[1] = zero;
    #pragma unroll
    for (int r = 0; r < 4; ++r) { m[r] = -1e30f; lsum[r] = 0.f; }

    for (int kc = 0; kc < 8; ++kc) {
        int buf = kc & 1;
        if (kc < 7) {
            int row = tid >> 2, g = tid & 3;
            const unsigned short* bp = &qkvb[(size_t)(base + (kc + 1) * 64 + row) * 384 + hd * 32 + g * 8];
            *(bf16x8*)&Ks[buf ^ 1][(row * 4 + (g ^ ((row >> 1) & 3))) * 8] = *(const bf16x8*)(bp + 128);
            bf16x8 vv = *(const bf16x8*)(bp + 256);
            #pragma unroll
            for (int j = 0; j < 8; ++j) {
                int d = g * 8 + j;
                Vt[buf ^ 1][d * 64 + (((row >> 3) ^ (d & 7)) << 3) + (row & 7)] = vv[j];
            }
        }
        f32x4 s[4];
        #pragma unroll
        for (int cf = 0; cf < 4; ++cf) {
            int kr = cf * 16 + lr;
            bf16x8 bk = *(const bf16x8*)&Ks[buf][(kr * 4 + (lg ^ ((kr >> 1) & 3))) * 8];
            s[cf] = __builtin_amdgcn_mfma_f32_16x16x32_bf16(aq, bk, zero, 0, 0, 0);
        }
        #pragma unroll
        for (int r = 0; r < 4; ++r) {
            float v0 = s[0][r] * SCL, v1 = s[1][r] * SCL, v2 = s[2][r] * SCL, v3 = s[3][r] * SCL;
            float rm = fmaxf(fmaxf(v0, v1), fmaxf(v2, v3));
            rm = fmaxf(rm, __shfl_xor(rm, 1));
            rm = fmaxf(rm, __shfl_xor(rm, 2));
            rm = fmaxf(rm, __shfl_xor(rm, 4));
            rm = fmaxf(rm, __shfl_xor(rm, 8));
            float mn = fmaxf(m[r], rm);
            float alpha = exp2f(m[r] - mn);
            float p0 = exp2f(v0 - mn), p1 = exp2f(v1 - mn), p2 = exp2f(v2 - mn), p3 = exp2f(v3 - mn);
            float ps = p0 + p1 + p2 + p3;
            ps += __shfl_xor(ps, 1); ps += __shfl_xor(ps, 2);
            ps += __shfl_xor(ps, 4); ps += __shfl_xor(ps, 8);
            lsum[r] = lsum[r] * alpha + ps;
            m[r] = mn;
            o[0][r] *= alpha; o[1][r] *= alpha;
            int prow = lg * 4 + r;
            int pg = prow * 64;
            Ps[w][pg + ((((lr     ) >> 3) ^ (prow & 7)) << 3) + (lr & 7)] = (short)f2bf(p0);
            Ps[w][pg + ((((lr + 16) >> 3) ^ (prow & 7)) << 3) + (lr & 7)] = (short)f2bf(p1);
            Ps[w][pg + ((((lr + 32) >> 3) ^ (prow & 7)) << 3) + (lr & 7)] = (short)f2bf(p2);
            Ps[w][pg + ((((lr + 48) >> 3) ^ (prow & 7)) << 3) + (lr & 7)] = (short)f2bf(p3);
        }
        bf16x8 pa[2];
        #pragma unroll
        for (int ak = 0; ak < 2; ++ak) {
            int g = ak * 4 + lg;
            pa[ak] = *(const bf16x8*)&Ps[w][(lr * 8 + (g ^ (lr & 7))) * 8];
        }
        #pragma unroll
        for (int of = 0; of < 2; ++of) {
            #pragma unroll
            for (int ak = 0; ak < 2; ++ak) {
                int d = of * 16 + lr;
                int gk = ak * 4 + lg;
                bf16x8 vb = *(const bf16x8*)&Vt[buf][(d * 8 + (gk ^ (d & 7))) * 8];
                o[of] = __builtin_amdgcn_mfma_f32_16x16x32_bf16(pa[ak], vb, o[of], 0, 0, 0);
            }
        }
        __syncthreads();
    }
    #pragma unroll
    for (int r = 0; r < 4; ++r) {
        float inv = 1.f / lsum[r];
        size_t nrow = (size_t)base + q0 + w * 16 + lg * 4 + r;
        ao16[nrow * 128 + hd * 32 + lr]      = f2bf(o[0][r] * inv);
        ao16[nrow * 128 + hd * 32 + 16 + lr] = f2bf(o[1][r] * inv);
    }
}

// ---------------- BN finalize (up to 2 norms per launch) ----------------
__global__ void bn_fin_k(const float* acc1, const float* g1, const float* b1, float* sf1,
                         const float* acc2, const float* g2, const float* b2, float* sf2)
{
    const float* acc = (blockIdx.x == 0) ? acc1 : acc2;
    const float* g   = (blockIdx.x == 0) ? g1 : g2;
    const float* b   = (blockIdx.x == 0) ? b1 : b2;
    float*       sf  = (blockIdx.x == 0) ? sf1 : sf2;
    if (acc == nullptr) return;
    int c = threadIdx.x;
    float mean = acc[c] * (1.f / N_NODES);
    float var  = acc[128 + c] * (1.f / N_NODES) - mean * mean;
    float sc   = g[c] * rsqrtf(var + 1e-5f);
    sf[c] = sc;
    sf[128 + c] = b[c] - mean * sc;
}

// ---------------- h = scale*t + shift (BN3 apply), dual f32 + bf16 write ----------------
__global__ __launch_bounds__(256) void bn_apply_k(const float* __restrict__ t, const float* __restrict__ sf,
                                                  float* __restrict__ h, unsigned short* __restrict__ h16)
{
    int idx = blockIdx.x * 256 + threadIdx.x;
    int cg = (idx & 31) * 4;
    float4 v  = *(const float4*)&t[idx * 4];
    float4 sc = *(const float4*)&sf[cg];
    float4 sh = *(const float4*)&sf[128 + cg];
    float4 o;
    o.x = v.x * sc.x + sh.x;
    o.y = v.y * sc.y + sh.y;
    o.z = v.z * sc.z + sh.z;
    o.w = v.w * sc.w + sh.w;
    *(float4*)&h[idx * 4] = o;
    short4v p;
    p[0] = (short)f2bf(o.x); p[1] = (short)f2bf(o.y);
    p[2] = (short)f2bf(o.z); p[3] = (short)f2bf(o.w);
    *(short4v*)&h16[idx * 4] = p;
}

// ---------------- global add pool ----------------
__global__ __launch_bounds__(128) void pool_k(const float* __restrict__ h, float* __restrict__ g)
{
    int b = blockIdx.x, c = threadIdx.x;
    float s = 0.f;
    for (int i = 0; i < NPG; ++i) s += h[(size_t)((b << 9) + i) * C_DIM + c];
    g[b * C_DIM + c] = s;
}

// ---------------- head MLP: [64,128]->64->32->1 ----------------
__global__ __launch_bounds__(256) void head_mlp_k(const float* __restrict__ g,
    const float* __restrict__ w1, const float* __restrict__ b1,
    const float* __restrict__ w2, const float* __restrict__ b2,
    const float* __restrict__ w3, const float* __restrict__ b3,
    float* __restrict__ out)
{
    __shared__ float gs[64 * 128];
    __shared__ float y1[64 * 64];
    __shared__ float y2[64 * 32];
    int tid = threadIdx.x;
    for (int r = 0; r < 32; ++r) gs[r * 256 + tid] = g[r * 256 + tid];
    __syncthreads();
    for (int t = 0; t < 16; ++t) {
        int idx = t * 256 + tid;
        int gi = idx >> 6, c = idx & 63;
        float s = b1[c];
        for (int k = 0; k < 128; ++k) s = fmaf(gs[gi * 128 + k], w1[k * 64 + c], s);
        y1[gi * 64 + c] = fmaxf(s, 0.f);
    }
    __syncthreads();
    for (int t = 0; t < 8; ++t) {
        int idx = t * 256 + tid;
        int gi = idx >> 5, c = idx & 31;
        float s = b2[c];
        for (int k = 0; k < 64; ++k) s = fmaf(y1[gi * 64 + k], w2[k * 32 + c], s);
        y2[gi * 32 + c] = fmaxf(s, 0.f);
    }
    __syncthreads();
    if (tid < 64) {
        float s = b3[0];
        for (int k = 0; k < 32; ++k) s = fmaf(y2[tid * 32 + k], w3[k], s);
        out[tid] = s;
    }
}

extern "C" void kernel_launch(void* const* d_in, const int* in_sizes, int n_in,
                              void* d_out, int out_size, void* d_ws, size_t ws_size,
                              hipStream_t stream)
{
    const int*   x        = (const int*)  d_in[0];
    const float* pe       = (const float*)d_in[1];
    const int*   ei       = (const int*)  d_in[2];
    const int*   eattr    = (const int*)  d_in[3];
    const float* node_emb = (const float*)d_in[5];
    const float* plw      = (const float*)d_in[6];
    const float* plb      = (const float*)d_in[7];
    const float* pe_g     = (const float*)d_in[8];
    const float* pe_b     = (const float*)d_in[9];
    const float* edge_emb = (const float*)d_in[10];
    const float* gw1      = (const float*)d_in[11];
    const float* gb1      = (const float*)d_in[12];
    const float* gw2      = (const float*)d_in[13];
    const float* gb2      = (const float*)d_in[14];
    const float* wqkv     = (const float*)d_in[15];
    const float* bqkv     = (const float*)d_in[16];
    const float* wo       = (const float*)d_in[17];
    const float* bo       = (const float*)d_in[18];
    const float* n1g      = (const float*)d_in[19];
    const float* n1b      = (const float*)d_in[20];
    const float* n2g      = (const float*)d_in[21];
    const float* n2b      = (const float*)d_in[22];
    const float* n3g      = (const float*)d_in[23];
    const float* n3b      = (const float*)d_in[24];
    const float* fw1      = (const float*)d_in[25];
    const float* fb1      = (const float*)d_in[26];
    const float* fw2      = (const float*)d_in[27];
    const float* fb2      = (const float*)d_in[28];
    const float* mw1      = (const float*)d_in[29];
    const float* mb1      = (const float*)d_in[30];
    const float* mw2      = (const float*)d_in[31];
    const float* mb2      = (const float*)d_in[32];
    const float* mw3      = (const float*)d_in[33];
    const float* mb3      = (const float*)d_in[34];

    float* wf  = (float*)d_ws;
    float* Hb  = wf;                                             // h [N,C] f32        [0,1NF)
    unsigned short* Zb16 = (unsigned short*)(wf + (size_t)NF);   // z / attn-out bf16  [1NF,1.5NF)
    float* T1  = wf + 2 * (size_t)NF;                            // t1 / t3 f32        [2NF,3NF)
    unsigned short* QKVb = (unsigned short*)(wf + 3 * (size_t)NF); // qkv bf16 [N,384] [3NF,4.5NF)
    float* T2  = wf + 3 * (size_t)NF;                            // t2 f32 (aliases dead qkv) [3NF,4NF)
    unsigned short* Y1b = (unsigned short*)(wf + 4 * (size_t)NF); // hidden bf16 [N,256] max [4NF,5NF)
    unsigned short* Hb16 = (unsigned short*)(wf + 5 * (size_t)NF); // h bf16 [N,C]     [5NF,5.5NF)
    int* wi     = (int*)(wf + 6 * (size_t)NF);
    int* indptr = wi;                      // N+1
    int* cnt    = wi + 32800;
    int* cnt2   = cnt + N_NODES;
    int* eid    = cnt2 + N_NODES;
    int* bsum   = eid + E_EDGES;           // 128
    int* bpre   = bsum + 128;              // 128
    float* st    = (float*)(bpre + 128);
    float* peacc = st;                     // 64
    float* bnacc = st + 64;                // 12*256
    float* pesf  = st + 64 + 12 * 256;     // 64
    float* bnsf  = pesf + 64;              // 12*256
    float* gpool = bnsf + 12 * 256;        // 64*128
    short* wT    = (short*)(gpool + 64 * 128);  // 655360 bf16 transposed weights

    const int* srcA = ei;
    const int* dstA = ei + E_EDGES;
    const int LSTR = 163840;

    hipMemsetAsync(peacc, 0, (64 + 12 * 256) * sizeof(float), stream);
    hipMemsetAsync(cnt, 0, 2 * N_NODES * sizeof(int), stream);

    wt_prep_k<<<640, 256, 0, stream>>>(gw1, gw2, wqkv, wo, fw1, fw2, wT);
    pe_stats_k<<<32, 256, 0, stream>>>(pe, peacc);
    pe_fin_k<<<1, 32, 0, stream>>>(peacc, pe_g, pe_b, pesf);
    h0_k<<<N_NODES / 2, 256, 0, stream>>>(x, pe, node_emb, plw, plb, pesf, Hb, Hb16);
    hist_k<<<E_EDGES / 256, 256, 0, stream>>>(dstA, cnt);
    bsum_k<<<128, 256, 0, stream>>>(cnt, bsum);
    bscan_k<<<1, 128, 0, stream>>>(bsum, bpre);
    indptr_k<<<128, 256, 0, stream>>>(cnt, bpre, indptr);
    scatter_k<<<E_EDGES / 256, 256, 0, stream>>>(dstA, indptr, cnt2, eid);

    for (int l = 0; l < L_LAYERS; ++l) {
        const short* gw1t  = wT + (size_t)l * LSTR;
        const short* gw2t  = wT + (size_t)l * LSTR + 16384;
        const short* wqkvt = wT + (size_t)l * LSTR + 32768;
        const short* wot   = wT + (size_t)l * LSTR + 81920;
        const short* fw1t  = wT + (size_t)l * LSTR + 98304;
        const short* fw2t  = wT + (size_t)l * LSTR + 131072;
        const float* lgb1  = gb1 + (size_t)l * 128;
        const float* lgb2  = gb2 + (size_t)l * 128;
        const float* lbqkv = bqkv + (size_t)l * 384;
        const float* lbo   = bo + (size_t)l * 128;
        const float* lfb1  = fb1 + (size_t)l * 256;
        const float* lfb2  = fb2 + (size_t)l * 128;
        float* acc1 = bnacc + (l * 3 + 0) * 256;  float* sf1v = bnsf + (l * 3 + 0) * 256;
        float* acc2 = bnacc + (l * 3 + 1) * 256;  float* sf2v = bnsf + (l * 3 + 1) * 256;
        float* acc3 = bnacc + (l * 3 + 2) * 256;  float* sf3v = bnsf + (l * 3 + 2) * 256;

        gine_gather_k<<<N_NODES / 4, 256, 0, stream>>>(Hb16, srcA, eattr, indptr, eid, edge_emb, Zb16);
        mgemm_k<128, 128, 0, 0, true,  false, true,  true ><<<dim3(1, 256), 256, 0, stream>>>(
            Zb16, nullptr, nullptr, nullptr, (const unsigned short*)gw1t, lgb1,
            nullptr, nullptr, nullptr, nullptr, Y1b, nullptr);
        mgemm_k<128, 128, 0, 1, false, true,  false, true ><<<dim3(1, 256), 256, 0, stream>>>(
            Y1b, nullptr, nullptr, nullptr, (const unsigned short*)gw2t, lgb2,
            Hb, nullptr, nullptr, nullptr, T1, acc1);
        mgemm_k<128, 384, 0, 0, false, false, true,  true ><<<dim3(3, 256), 256, 0, stream>>>(
            Hb16, nullptr, nullptr, nullptr, (const unsigned short*)wqkvt, lbqkv,
            nullptr, nullptr, nullptr, nullptr, QKVb, nullptr);
        attn_mfma_k<<<dim3(8, 4, 64), 256, 0, stream>>>(QKVb, Zb16);
        mgemm_k<128, 128, 0, 1, false, true,  false, true ><<<dim3(1, 256), 256, 0, stream>>>(
            Zb16, nullptr, nullptr, nullptr, (const unsigned short*)wot, lbo,
            Hb, nullptr, nullptr, nullptr, T2, acc2);
        bn_fin_k<<<2, 128, 0, stream>>>(acc1, n1g + l * 128, n1b + l * 128, sf1v,
                                        acc2, n2g + l * 128, n2b + l * 128, sf2v);
        mgemm_k<128, 256, 1, 0, true,  false, true,  false><<<dim3(2, 256), 256, 0, stream>>>(
            T1, T2, sf1v, sf2v, (const unsigned short*)fw1t, lfb1,
            nullptr, nullptr, nullptr, nullptr, Y1b, nullptr);
        mgemm_k<256, 128, 0, 2, false, true,  false, true ><<<dim3(1, 256), 256, 0, stream>>>(
            Y1b, nullptr, nullptr, nullptr, (const unsigned short*)fw2t, lfb2,
            T1, T2, sf1v, sf2v, T1, acc3);
        bn_fin_k<<<1, 128, 0, stream>>>(acc3, n3g + l * 128, n3b + l * 128, sf3v,
                                        nullptr, nullptr, nullptr, nullptr);
        bn_apply_k<<<NF / 1024, 256, 0, stream>>>(T1, sf3v, Hb, Hb16);
    }
    pool_k<<<B_GR, 128, 0, stream>>>(Hb, gpool);
    head_mlp_k<<<1, 256, 0, stream>>>(gpool, mw1, mb1, mw2, mb2, mw3, mb3, (float*)d_out);
}

// Round 5
// 919.625 us; speedup vs baseline: 2.4197x; 1.0109x over previous
//
#include <hip/hip_runtime.h>
#include <math.h>
#include <cstddef>

#define N_NODES 32768
#define C_DIM   128
#define E_EDGES 262144
#define B_GR    64
#define NPG     512
#define WALK_D  20
#define L_LAYERS 4

static constexpr int NF = N_NODES * C_DIM;  // 4,194,304 floats per [N,C] tensor

typedef __attribute__((ext_vector_type(8))) short bf16x8;
typedef __attribute__((ext_vector_type(4))) float f32x4;
typedef __attribute__((ext_vector_type(4))) short short4v;

__device__ inline unsigned short f2bf(float f)
{
    union { float f; unsigned u; } v; v.f = f;
    unsigned r = v.u + 0x7fff + ((v.u >> 16) & 1);
    return (unsigned short)(r >> 16);
}
__device__ inline float bf2f_lo(unsigned u) { return __uint_as_float(u << 16); }
__device__ inline float bf2f_hi(unsigned u) { return __uint_as_float(u & 0xffff0000u); }

// ---------------- PE batch-norm statistics: register-private + wave reduce ----------------
__global__ __launch_bounds__(256) void pe_stats_k(const float* __restrict__ pe, float* __restrict__ acc)
{
    int gt = blockIdx.x * 256 + threadIdx.x;   // 8192 threads, 4 rows each
    float s[WALK_D], q[WALK_D];
    #pragma unroll
    for (int c = 0; c < WALK_D; ++c) { s[c] = 0.f; q[c] = 0.f; }
    for (int r = 0; r < 4; ++r) {
        const float* row = &pe[(size_t)(gt + r * 8192) * WALK_D];
        float v[20];
        #pragma unroll
        for (int j = 0; j < 5; ++j) *(float4*)&v[j * 4] = *(const float4*)(row + j * 4);
        #pragma unroll
        for (int c = 0; c < WALK_D; ++c) { s[c] += v[c]; q[c] += v[c] * v[c]; }
    }
    #pragma unroll
    for (int c = 0; c < WALK_D; ++c) {
        float ss = s[c], qq = q[c];
        #pragma unroll
        for (int m = 1; m < 64; m <<= 1) { ss += __shfl_xor(ss, m); qq += __shfl_xor(qq, m); }
        if ((threadIdx.x & 63) == 0) { atomicAdd(&acc[c], ss); atomicAdd(&acc[32 + c], qq); }
    }
}

__global__ void pe_fin_k(const float* __restrict__ acc, const float* __restrict__ g,
                         const float* __restrict__ b, float* __restrict__ sf)
{
    int c = threadIdx.x;
    if (c >= WALK_D) return;
    float mean = acc[c] * (1.f / N_NODES);
    float var  = acc[32 + c] * (1.f / N_NODES) - mean * mean;
    float sc   = g[c] * rsqrtf(var + 1e-5f);
    sf[c] = sc;
    sf[32 + c] = b[c] - mean * sc;
}

// ---------------- initial embedding h0 = [node_emb[x], BN(pe) @ pe_lin] ----------------
__global__ __launch_bounds__(256) void h0_k(const int* __restrict__ x, const float* __restrict__ pe,
    const float* __restrict__ node_emb, const float* __restrict__ plw, const float* __restrict__ plb,
    const float* __restrict__ pesf, float* __restrict__ h, unsigned short* __restrict__ h16)
{
    int tid = threadIdx.x;
    int i = blockIdx.x * 2 + (tid >> 7);
    int c = tid & 127;
    float v;
    if (c < 120) {
        v = node_emb[x[i] * 120 + c];
    } else {
        int pc = c - 120;
        v = plb[pc];
        #pragma unroll
        for (int k = 0; k < WALK_D; ++k) {
            float pn = pe[i * WALK_D + k] * pesf[k] + pesf[32 + k];
            v = fmaf(pn, plw[k * 8 + pc], v);
        }
    }
    h[i * C_DIM + c] = v;
    h16[i * C_DIM + c] = f2bf(v);
}

// ---------------- CSR build (by destination) ----------------
__global__ __launch_bounds__(256) void hist_k(const int* __restrict__ dst, int* __restrict__ cnt)
{
    int e = blockIdx.x * 256 + threadIdx.x;
    atomicAdd(&cnt[dst[e]], 1);
}

__global__ __launch_bounds__(256) void bsum_k(const int* __restrict__ cnt, int* __restrict__ bsum)
{
    __shared__ int ws[4];
    int b = blockIdx.x, t = threadIdx.x;
    int v = cnt[b * 256 + t];
    #pragma unroll
    for (int m = 1; m < 64; m <<= 1) v += __shfl_xor(v, m);
    if ((t & 63) == 0) ws[t >> 6] = v;
    __syncthreads();
    if (t == 0) bsum[b] = ws[0] + ws[1] + ws[2] + ws[3];
}

__global__ __launch_bounds__(128) void bscan_k(const int* __restrict__ bsum, int* __restrict__ bpre)
{
    __shared__ int s[128];
    int t = threadIdx.x;
    int v = bsum[t];
    s[t] = v;
    __syncthreads();
    for (int off = 1; off < 128; off <<= 1) {
        int u = (t >= off) ? s[t - off] : 0;
        __syncthreads();
        s[t] += u;
        __syncthreads();
    }
    bpre[t] = s[t] - v;
}

__global__ __launch_bounds__(256) void indptr_k(const int* __restrict__ cnt, const int* __restrict__ bpre,
                                                int* __restrict__ indptr)
{
    __shared__ int s[256];
    int b = blockIdx.x, t = threadIdx.x;
    int v = cnt[b * 256 + t];
    s[t] = v;
    __syncthreads();
    for (int off = 1; off < 256; off <<= 1) {
        int u = (t >= off) ? s[t - off] : 0;
        __syncthreads();
        s[t] += u;
        __syncthreads();
    }
    indptr[b * 256 + t] = bpre[b] + s[t] - v;
    if (b == 127 && t == 255) indptr[N_NODES] = E_EDGES;
}

__global__ __launch_bounds__(256) void scatter_k(const int* __restrict__ dst, const int* __restrict__ indptr,
                                                 int* __restrict__ cur, int* __restrict__ eid)
{
    int e = blockIdx.x * 256 + threadIdx.x;
    int d = dst[e];
    int pos = atomicAdd(&cur[d], 1);
    eid[indptr[d] + pos] = e;
}

// ---------------- GINE message aggregation (bf16 in/out): z = h + sum_in relu(h[src]+ee) ----------------
__global__ __launch_bounds__(256) void gine_gather_k(const unsigned short* __restrict__ h16,
    const int* __restrict__ src, const int* __restrict__ attr,
    const int* __restrict__ indptr, const int* __restrict__ eid,
    const float* __restrict__ edge_emb, unsigned short* __restrict__ z16)
{
    __shared__ float ee[4 * C_DIM];
    int tid = threadIdx.x;
    ee[tid] = edge_emb[tid];
    ee[tid + 256] = edge_emb[tid + 256];
    __syncthreads();
    int i = blockIdx.x * 4 + (tid >> 6);
    int c = (tid & 63) * 2;
    int p0 = indptr[i], p1 = indptr[i + 1];
    float s0 = 0.f, s1 = 0.f;
    for (int p = p0; p < p1; ++p) {
        int e  = eid[p];
        int sv = src[e];
        int av = attr[e];
        unsigned u = *(const unsigned*)&h16[(size_t)sv * C_DIM + c];
        float m0 = bf2f_lo(u) + ee[av * C_DIM + c];
        float m1 = bf2f_hi(u) + ee[av * C_DIM + c + 1];
        s0 += fmaxf(m0, 0.f);
        s1 += fmaxf(m1, 0.f);
    }
    unsigned us = *(const unsigned*)&h16[(size_t)i * C_DIM + c];
    s0 += bf2f_lo(us);
    s1 += bf2f_hi(us);
    unsigned out = (unsigned)f2bf(s0) | ((unsigned)f2bf(s1) << 16);
    *(unsigned*)&z16[(size_t)i * C_DIM + c] = out;
}

// ---------------- weight prep: W[K][N] f32 -> Wt[N][K] bf16, all 24 matrices ----------------
__global__ __launch_bounds__(256) void wt_prep_k(
    const float* __restrict__ gw1, const float* __restrict__ gw2,
    const float* __restrict__ wqkv, const float* __restrict__ wo,
    const float* __restrict__ fw1, const float* __restrict__ fw2,
    short* __restrict__ out)
{
    __shared__ float ts[32][36];
    int b = blockIdx.x;
    int l = b / 160, t = b % 160;
    const float* src; int K, N; size_t obase; int tile;
    if (t < 16)       { src = gw1  + (size_t)l * 16384; K = 128; N = 128; obase = (size_t)l * 163840 + 0;      tile = t; }
    else if (t < 32)  { src = gw2  + (size_t)l * 16384; K = 128; N = 128; obase = (size_t)l * 163840 + 16384;  tile = t - 16; }
    else if (t < 80)  { src = wqkv + (size_t)l * 49152; K = 128; N = 384; obase = (size_t)l * 163840 + 32768;  tile = t - 32; }
    else if (t < 96)  { src = wo   + (size_t)l * 16384; K = 128; N = 128; obase = (size_t)l * 163840 + 81920;  tile = t - 80; }
    else if (t < 128) { src = fw1  + (size_t)l * 32768; K = 128; N = 256; obase = (size_t)l * 163840 + 98304;  tile = t - 96; }
    else              { src = fw2  + (size_t)l * 32768; K = 256; N = 128; obase = (size_t)l * 163840 + 131072; tile = t - 128; }
    int ntN = N / 32;
    int tk = tile / ntN, tn = tile % ntN;
    int tid = threadIdx.x;
    int r = tid >> 3, c4 = (tid & 7) * 4;
    *(float4*)&ts[r][c4] = *(const float4*)&src[(size_t)(tk * 32 + r) * N + tn * 32 + c4];
    __syncthreads();
    int n = tid >> 3, k4 = (tid & 7) * 4;
    short4v pk;
    #pragma unroll
    for (int i2 = 0; i2 < 4; ++i2) pk[i2] = (short)f2bf(ts[k4 + i2][n]);
    *(short4v*)&out[obase + (size_t)(tn * 32 + n) * K + tk * 32 + k4] = pk;
}

// ---------------- MFMA bf16 GEMM: Cout = op(A) @ Bt^T (+bias,+res,relu,BN-stats) ----------------
template<int KD, int NC, int AMODE, int RESMODE, bool RELU, bool STATS, bool OUTBF, bool ABF>
__global__ __launch_bounds__(256) void mgemm_k(
    const void* __restrict__ Av, const float* __restrict__ A2,
    const float* __restrict__ affA1, const float* __restrict__ affA2,
    const unsigned short* __restrict__ Bt, const float* __restrict__ bias,
    const float* __restrict__ R1, const float* __restrict__ R2,
    const float* __restrict__ affR1, const float* __restrict__ affR2,
    void* __restrict__ Cout, float* __restrict__ stats)
{
    __shared__ short As[16384];   // [128 rows][128 k] bf16, XOR-swizzled granules
    __shared__ short Bs[16384];   // [128 cols][128 k] bf16
    const int tid = threadIdx.x;
    const int w = tid >> 6;
    const int lane = tid & 63;
    const int lr = lane & 15, lg = lane >> 4;
    const int row0 = blockIdx.y * 128;
    const int col0 = blockIdx.x * 128;

    const f32x4 zero = {0.f, 0.f, 0.f, 0.f};
    f32x4 acc[2][8];
    #pragma unroll
    for (int i = 0; i < 2; ++i)
        #pragma unroll
        for (int cf = 0; cf < 8; ++cf) acc[i][cf] = zero;

    for (int kt = 0; kt < KD / 128; ++kt) {
        if (kt > 0) __syncthreads();
        #pragma unroll
        for (int it = 0; it < 8; ++it) {
            int gid = it * 256 + tid;
            int row = gid >> 4, g = gid & 15;
            bf16x8 pk;
            if (ABF) {
                pk = *(const bf16x8*)&((const unsigned short*)Av)[(size_t)(row0 + row) * KD + kt * 128 + g * 8];
            } else {
                const float* Af = (const float*)Av;
                const float* ap = &Af[(size_t)(row0 + row) * KD + kt * 128 + g * 8];
                float v[8];
                *(float4*)&v[0] = *(const float4*)ap;
                *(float4*)&v[4] = *(const float4*)(ap + 4);
                if (AMODE == 1) {
                    const float* ap2 = &A2[(size_t)(row0 + row) * KD + kt * 128 + g * 8];
                    float u[8];
                    *(float4*)&u[0] = *(const float4*)ap2;
                    *(float4*)&u[4] = *(const float4*)(ap2 + 4);
                    #pragma unroll
                    for (int j = 0; j < 8; ++j) {
                        int ck = g * 8 + j;
                        v[j] = v[j] * affA1[ck] + affA1[128 + ck] + u[j] * affA2[ck] + affA2[128 + ck];
                    }
                }
                #pragma unroll
                for (int j = 0; j < 8; ++j) pk[j] = (short)f2bf(v[j]);
            }
            *(bf16x8*)&As[(row * 16 + (g ^ (row & 7))) * 8] = pk;
            bf16x8 bv = *(const bf16x8*)&Bt[(size_t)(col0 + row) * KD + kt * 128 + g * 8];
            *(bf16x8*)&Bs[(row * 16 + (g ^ (row & 7))) * 8] = bv;
        }
        __syncthreads();
        #pragma unroll
        for (int ks = 0; ks < 4; ++ks) {
            bf16x8 af[2], bfr[8];
            #pragma unroll
            for (int i = 0; i < 2; ++i) {
                int row = w * 32 + i * 16 + lr;
                int g = ks * 4 + lg;
                af[i] = *(const bf16x8*)&As[(row * 16 + (g ^ (row & 7))) * 8];
            }
            #pragma unroll
            for (int cf = 0; cf < 8; ++cf) {
                int c = cf * 16 + lr;
                int g = ks * 4 + lg;
                bfr[cf] = *(const bf16x8*)&Bs[(c * 16 + (g ^ (c & 7))) * 8];
            }
            #pragma unroll
            for (int i = 0; i < 2; ++i)
                #pragma unroll
                for (int cf = 0; cf < 8; ++cf)
                    acc[i][cf] = __builtin_amdgcn_mfma_f32_16x16x32_bf16(af[i], bfr[cf], acc[i][cf], 0, 0, 0);
        }
    }

    float* cs = (float*)As;       // alias LDS after compute
    float* cq = cs + 128;
    if (STATS) {
        __syncthreads();
        if (tid < 128) { cs[tid] = 0.f; cq[tid] = 0.f; }
        __syncthreads();
    }
    float bs_v[8];
    #pragma unroll
    for (int cf = 0; cf < 8; ++cf) bs_v[cf] = bias[col0 + cf * 16 + lr];
    float rs1[8], ro1[8], rs2[8], ro2[8];
    if (RESMODE == 2) {
        #pragma unroll
        for (int cf = 0; cf < 8; ++cf) {
            int c = cf * 16 + lr;
            rs1[cf] = affR1[c]; ro1[cf] = affR1[128 + c];
            rs2[cf] = affR2[c]; ro2[cf] = affR2[128 + c];
        }
    }
    float colS[8], colQ[8];
    #pragma unroll
    for (int cf = 0; cf < 8; ++cf) { colS[cf] = 0.f; colQ[cf] = 0.f; }
    #pragma unroll
    for (int i = 0; i < 2; ++i) {
        #pragma unroll
        for (int r = 0; r < 4; ++r) {
            size_t grow = row0 + w * 32 + i * 16 + lg * 4 + r;
            #pragma unroll
            for (int cf = 0; cf < 8; ++cf) {
                int c = col0 + cf * 16 + lr;
                float val = acc[i][cf][r] + bs_v[cf];
                if (RESMODE == 1) val += R1[grow * NC + c];
                if (RESMODE == 2) {
                    val += R1[grow * 128 + c] * rs1[cf] + ro1[cf]
                         + R2[grow * 128 + c] * rs2[cf] + ro2[cf];
                }
                if (RELU) val = fmaxf(val, 0.f);
                if (OUTBF) ((unsigned short*)Cout)[grow * NC + c] = f2bf(val);
                else       ((float*)Cout)[grow * NC + c] = val;
                if (STATS) { colS[cf] += val; colQ[cf] += val * val; }
            }
        }
    }
    if (STATS) {
        #pragma unroll
        for (int cf = 0; cf < 8; ++cf) {
            float s = colS[cf], q = colQ[cf];
            s += __shfl_xor(s, 16); s += __shfl_xor(s, 32);
            q += __shfl_xor(q, 16); q += __shfl_xor(q, 32);
            if (lg == 0) { atomicAdd(&cs[cf * 16 + lr], s); atomicAdd(&cq[cf * 16 + lr], q); }
        }
        __syncthreads();
        if (tid < 128) {
            atomicAdd(&stats[tid], cs[tid]);
            atomicAdd(&stats[128 + tid], cq[tid]);
        }
    }
}

// ---------------- fused GINE MLP: T1 = relu(z@W1+b1)@W2+b2 + h, BN1 stats ----------------
// Bit-identical to the unfused mgemm pair: Y1 round-trips through LDS at the same
// bf16 rounding point and identical swizzled positions.
__global__ __launch_bounds__(256) void gine_mlp_k(
    const unsigned short* __restrict__ z16,
    const unsigned short* __restrict__ W1t, const float* __restrict__ b1,
    const unsigned short* __restrict__ W2t, const float* __restrict__ b2,
    const float* __restrict__ Hres,
    float* __restrict__ T1out, float* __restrict__ stats)
{
    __shared__ short As[16384];
    __shared__ short Bs[16384];
    const int tid = threadIdx.x;
    const int w = tid >> 6;
    const int lane = tid & 63;
    const int lr = lane & 15, lg = lane >> 4;
    const int row0 = blockIdx.x * 128;
    const f32x4 zero = {0.f, 0.f, 0.f, 0.f};

    // stage z -> As, W1 -> Bs
    #pragma unroll
    for (int it = 0; it < 8; ++it) {
        int gid = it * 256 + tid;
        int row = gid >> 4, g = gid & 15;
        bf16x8 av = *(const bf16x8*)&z16[(size_t)(row0 + row) * 128 + g * 8];
        *(bf16x8*)&As[(row * 16 + (g ^ (row & 7))) * 8] = av;
        bf16x8 bv = *(const bf16x8*)&W1t[(size_t)row * 128 + g * 8];
        *(bf16x8*)&Bs[(row * 16 + (g ^ (row & 7))) * 8] = bv;
    }
    __syncthreads();

    f32x4 acc[2][8];
    #pragma unroll
    for (int i = 0; i < 2; ++i)
        #pragma unroll
        for (int cf = 0; cf < 8; ++cf) acc[i][cf] = zero;
    #pragma unroll
    for (int ks = 0; ks < 4; ++ks) {
        bf16x8 af[2], bfr[8];
        #pragma unroll
        for (int i = 0; i < 2; ++i) {
            int row = w * 32 + i * 16 + lr;
            int g = ks * 4 + lg;
            af[i] = *(const bf16x8*)&As[(row * 16 + (g ^ (row & 7))) * 8];
        }
        #pragma unroll
        for (int cf = 0; cf < 8; ++cf) {
            int c = cf * 16 + lr;
            int g = ks * 4 + lg;
            bfr[cf] = *(const bf16x8*)&Bs[(c * 16 + (g ^ (c & 7))) * 8];
        }
        #pragma unroll
        for (int i = 0; i < 2; ++i)
            #pragma unroll
            for (int cf = 0; cf < 8; ++cf)
                acc[i][cf] = __builtin_amdgcn_mfma_f32_16x16x32_bf16(af[i], bfr[cf], acc[i][cf], 0, 0, 0);
    }
    __syncthreads();   // all As(z)/Bs(W1) reads complete

    // Y1 = f2bf(relu(acc + b1)) -> As (same swizzled positions the unfused staging used)
    {
        float bias1[8];
        #pragma unroll
        for (int cf = 0; cf < 8; ++cf) bias1[cf] = b1[cf * 16 + lr];
        #pragma unroll
        for (int i = 0; i < 2; ++i) {
            #pragma unroll
            for (int r = 0; r < 4; ++r) {
                int row = w * 32 + i * 16 + lg * 4 + r;
                #pragma unroll
                for (int cf = 0; cf < 8; ++cf) {
                    int col = cf * 16 + lr;
                    float val = fmaxf(acc[i][cf][r] + bias1[cf], 0.f);
                    As[(row * 16 + ((col >> 3) ^ (row & 7))) * 8 + (col & 7)] = (short)f2bf(val);
                }
            }
        }
    }
    // stage W2 -> Bs
    #pragma unroll
    for (int it = 0; it < 8; ++it) {
        int gid = it * 256 + tid;
        int row = gid >> 4, g = gid & 15;
        bf16x8 bv = *(const bf16x8*)&W2t[(size_t)row * 128 + g * 8];
        *(bf16x8*)&Bs[(row * 16 + (g ^ (row & 7))) * 8] = bv;
    }
    __syncthreads();

    #pragma unroll
    for (int i = 0; i < 2; ++i)
        #pragma unroll
        for (int cf = 0; cf < 8; ++cf) acc[i][cf] = zero;
    #pragma unroll
    for (int ks = 0; ks < 4; ++ks) {
        bf16x8 af[2], bfr[8];
        #pragma unroll
        for (int i = 0; i < 2; ++i) {
            int row = w * 32 + i * 16 + lr;
            int g = ks * 4 + lg;
            af[i] = *(const bf16x8*)&As[(row * 16 + (g ^ (row & 7))) * 8];
        }
        #pragma unroll
        for (int cf = 0; cf < 8; ++cf) {
            int c = cf * 16 + lr;
            int g = ks * 4 + lg;
            bfr[cf] = *(const bf16x8*)&Bs[(c * 16 + (g ^ (c & 7))) * 8];
        }
        #pragma unroll
        for (int i = 0; i < 2; ++i)
            #pragma unroll
            for (int cf = 0; cf < 8; ++cf)
                acc[i][cf] = __builtin_amdgcn_mfma_f32_16x16x32_bf16(af[i], bfr[cf], acc[i][cf], 0, 0, 0);
    }

    // epilogue: + b2 + Hres, write f32, BN1 stats (identical to mgemm RESMODE1+STATS)
    float* cs = (float*)As;
    float* cq = cs + 128;
    __syncthreads();
    if (tid < 128) { cs[tid] = 0.f; cq[tid] = 0.f; }
    __syncthreads();
    float bs_v[8];
    #pragma unroll
    for (int cf = 0; cf < 8; ++cf) bs_v[cf] = b2[cf * 16 + lr];
    float colS[8], colQ[8];
    #pragma unroll
    for (int cf = 0; cf < 8; ++cf) { colS[cf] = 0.f; colQ[cf] = 0.f; }
    #pragma unroll
    for (int i = 0; i < 2; ++i) {
        #pragma unroll
        for (int r = 0; r < 4; ++r) {
            size_t grow = row0 + w * 32 + i * 16 + lg * 4 + r;
            #pragma unroll
            for (int cf = 0; cf < 8; ++cf) {
                int c = cf * 16 + lr;
                float val = acc[i][cf][r] + bs_v[cf] + Hres[grow * 128 + c];
                T1out[grow * 128 + c] = val;
                colS[cf] += val; colQ[cf] += val * val;
            }
        }
    }
    #pragma unroll
    for (int cf = 0; cf < 8; ++cf) {
        float s = colS[cf], q = colQ[cf];
        s += __shfl_xor(s, 16); s += __shfl_xor(s, 32);
        q += __shfl_xor(q, 16); q += __shfl_xor(q, 32);
        if (lg == 0) { atomicAdd(&cs[cf * 16 + lr], s); atomicAdd(&cq[cf * 16 + lr], q); }
    }
    __syncthreads();
    if (tid < 128) {
        atomicAdd(&stats[tid], cs[tid]);
        atomicAdd(&stats[128 + tid], cq[tid]);
    }
}

// ---------------- MFMA flash attention: per (64-q tile, head, graph), bf16 out ----------------
__global__ __launch_bounds__(256) void attn_mfma_k(const unsigned short* __restrict__ qkvb,
                                                   unsigned short* __restrict__ ao16)
{
    __shared__ short Qs[2048];      // [64 q][32 d] swizzled
    __shared__ short Ks[2][2048];   // [64 k][32 d] swizzled, double-buffered
    __shared__ short Vt[2][2048];   // [32 d][64 k] swizzled, double-buffered
    __shared__ short Ps[4][1024];   // per-wave [16 q][64 k]
    const int tid = threadIdx.x;
    const int w = tid >> 6, lane = tid & 63;
    const int lr = lane & 15, lg = lane >> 4;
    const int q0 = blockIdx.x * 64;
    const int hd = blockIdx.y;
    const int base = blockIdx.z * NPG;
    const float SCL = 0.17677669529663687f * 1.44269504089f;  // 1/sqrt(32) * log2(e)

    {
        int row = tid >> 2, g = tid & 3;
        bf16x8 qv = *(const bf16x8*)&qkvb[(size_t)(base + q0 + row) * 384 + hd * 32 + g * 8];
        *(bf16x8*)&Qs[(row * 4 + (g ^ ((row >> 1) & 3))) * 8] = qv;
        const unsigned short* bp = &qkvb[(size_t)(base + row) * 384 + hd * 32 + g * 8];
        *(bf16x8*)&Ks[0][(row * 4 + (g ^ ((row >> 1) & 3))) * 8] = *(const bf16x8*)(bp + 128);
        bf16x8 vv = *(const bf16x8*)(bp + 256);
        #pragma unroll
        for (int j = 0; j < 8; ++j) {
            int d = g * 8 + j;
            Vt[0][d * 64 + (((row >> 3) ^ (d & 7)) << 3) + (row & 7)] = vv[j];
        }
    }
    __syncthreads();
    const int qrow = w * 16 + lr;
    bf16x8 aq = *(const bf16x8*)&Qs[(qrow * 4 + (lg ^ ((qrow >> 1) & 3))) * 8];
    float m[4], lsum[4];
    const f32x4 zero = {0.f, 0.f, 0.f, 0.f};
    f32x4 o[2];
    o[0] = zero; o[1] = zero;
    #pragma unroll
    for (int r = 0; r < 4; ++r) { m[r] = -1e30f; lsum[r] = 0.f; }

    for (int kc = 0; kc < 8; ++kc) {
        int buf = kc & 1;
        if (kc < 7) {
            int row = tid >> 2, g = tid & 3;
            const unsigned short* bp = &qkvb[(size_t)(base + (kc + 1) * 64 + row) * 384 + hd * 32 + g * 8];
            *(bf16x8*)&Ks[buf ^ 1][(row * 4 + (g ^ ((row >> 1) & 3))) * 8] = *(const bf16x8*)(bp + 128);
            bf16x8 vv = *(const bf16x8*)(bp + 256);
            #pragma unroll
            for (int j = 0; j < 8; ++j) {
                int d = g * 8 + j;
                Vt[buf ^ 1][d * 64 + (((row >> 3) ^ (d & 7)) << 3) + (row & 7)] = vv[j];
            }
        }
        f32x4 s[4];
        #pragma unroll
        for (int cf = 0; cf < 4; ++cf) {
            int kr = cf * 16 + lr;
            bf16x8 bk = *(const bf16x8*)&Ks[buf][(kr * 4 + (lg ^ ((kr >> 1) & 3))) * 8];
            s[cf] = __builtin_amdgcn_mfma_f32_16x16x32_bf16(aq, bk, zero, 0, 0, 0);
        }
        #pragma unroll
        for (int r = 0; r < 4; ++r) {
            float v0 = s[0][r] * SCL, v1 = s[1][r] * SCL, v2 = s[2][r] * SCL, v3 = s[3][r] * SCL;
            float rm = fmaxf(fmaxf(v0, v1), fmaxf(v2, v3));
            rm = fmaxf(rm, __shfl_xor(rm, 1));
            rm = fmaxf(rm, __shfl_xor(rm, 2));
            rm = fmaxf(rm, __shfl_xor(rm, 4));
            rm = fmaxf(rm, __shfl_xor(rm, 8));
            float mn = fmaxf(m[r], rm);
            float alpha = exp2f(m[r] - mn);
            float p0 = exp2f(v0 - mn), p1 = exp2f(v1 - mn), p2 = exp2f(v2 - mn), p3 = exp2f(v3 - mn);
            float ps = p0 + p1 + p2 + p3;
            ps += __shfl_xor(ps, 1); ps += __shfl_xor(ps, 2);
            ps += __shfl_xor(ps, 4); ps += __shfl_xor(ps, 8);
            lsum[r] = lsum[r] * alpha + ps;
            m[r] = mn;
            o[0][r] *= alpha; o[1][r] *= alpha;
            int prow = lg * 4 + r;
            int pg = prow * 64;
            Ps[w][pg + ((((lr     ) >> 3) ^ (prow & 7)) << 3) + (lr & 7)] = (short)f2bf(p0);
            Ps[w][pg + ((((lr + 16) >> 3) ^ (prow & 7)) << 3) + (lr & 7)] = (short)f2bf(p1);
            Ps[w][pg + ((((lr + 32) >> 3) ^ (prow & 7)) << 3) + (lr & 7)] = (short)f2bf(p2);
            Ps[w][pg + ((((lr + 48) >> 3) ^ (prow & 7)) << 3) + (lr & 7)] = (short)f2bf(p3);
        }
        bf16x8 pa[2];
        #pragma unroll
        for (int ak = 0; ak < 2; ++ak) {
            int g = ak * 4 + lg;
            pa[ak] = *(const bf16x8*)&Ps[w][(lr * 8 + (g ^ (lr & 7))) * 8];
        }
        #pragma unroll
        for (int of = 0; of < 2; ++of) {
            #pragma unroll
            for (int ak = 0; ak < 2; ++ak) {
                int d = of * 16 + lr;
                int gk = ak * 4 + lg;
                bf16x8 vb = *(const bf16x8*)&Vt[buf][(d * 8 + (gk ^ (d & 7))) * 8];
                o[of] = __builtin_amdgcn_mfma_f32_16x16x32_bf16(pa[ak], vb, o[of], 0, 0, 0);
            }
        }
        __syncthreads();
    }
    #pragma unroll
    for (int r = 0; r < 4; ++r) {
        float inv = 1.f / lsum[r];
        size_t nrow = (size_t)base + q0 + w * 16 + lg * 4 + r;
        ao16[nrow * 128 + hd * 32 + lr]      = f2bf(o[0][r] * inv);
        ao16[nrow * 128 + hd * 32 + 16 + lr] = f2bf(o[1][r] * inv);
    }
}

// ---------------- BN finalize (up to 2 norms per launch) ----------------
__global__ void bn_fin_k(const float* acc1, const float* g1, const float* b1, float* sf1,
                         const float* acc2, const float* g2, const float* b2, float* sf2)
{
    const float* acc = (blockIdx.x == 0) ? acc1 : acc2;
    const float* g   = (blockIdx.x == 0) ? g1 : g2;
    const float* b   = (blockIdx.x == 0) ? b1 : b2;
    float*       sf  = (blockIdx.x == 0) ? sf1 : sf2;
    if (acc == nullptr) return;
    int c = threadIdx.x;
    float mean = acc[c] * (1.f / N_NODES);
    float var  = acc[128 + c] * (1.f / N_NODES) - mean * mean;
    float sc   = g[c] * rsqrtf(var + 1e-5f);
    sf[c] = sc;
    sf[128 + c] = b[c] - mean * sc;
}

// ---------------- h = scale*t + shift (BN3 apply), dual f32 + bf16 write ----------------
__global__ __launch_bounds__(256) void bn_apply_k(const float* __restrict__ t, const float* __restrict__ sf,
                                                  float* __restrict__ h, unsigned short* __restrict__ h16)
{
    int idx = blockIdx.x * 256 + threadIdx.x;
    int cg = (idx & 31) * 4;
    float4 v  = *(const float4*)&t[idx * 4];
    float4 sc = *(const float4*)&sf[cg];
    float4 sh = *(const float4*)&sf[128 + cg];
    float4 o;
    o.x = v.x * sc.x + sh.x;
    o.y = v.y * sc.y + sh.y;
    o.z = v.z * sc.z + sh.z;
    o.w = v.w * sc.w + sh.w;
    *(float4*)&h[idx * 4] = o;
    short4v p;
    p[0] = (short)f2bf(o.x); p[1] = (short)f2bf(o.y);
    p[2] = (short)f2bf(o.z); p[3] = (short)f2bf(o.w);
    *(short4v*)&h16[idx * 4] = p;
}

// ---------------- global add pool ----------------
__global__ __launch_bounds__(128) void pool_k(const float* __restrict__ h, float* __restrict__ g)
{
    int b = blockIdx.x, c = threadIdx.x;
    float s = 0.f;
    for (int i = 0; i < NPG; ++i) s += h[(size_t)((b << 9) + i) * C_DIM + c];
    g[b * C_DIM + c] = s;
}

// ---------------- head MLP: [64,128]->64->32->1 ----------------
__global__ __launch_bounds__(256) void head_mlp_k(const float* __restrict__ g,
    const float* __restrict__ w1, const float* __restrict__ b1,
    const float* __restrict__ w2, const float* __restrict__ b2,
    const float* __restrict__ w3, const float* __restrict__ b3,
    float* __restrict__ out)
{
    __shared__ float gs[64 * 128];
    __shared__ float y1[64 * 64];
    __shared__ float y2[64 * 32];
    int tid = threadIdx.x;
    for (int r = 0; r < 32; ++r) gs[r * 256 + tid] = g[r * 256 + tid];
    __syncthreads();
    for (int t = 0; t < 16; ++t) {
        int idx = t * 256 + tid;
        int gi = idx >> 6, c = idx & 63;
        float s = b1[c];
        for (int k = 0; k < 128; ++k) s = fmaf(gs[gi * 128 + k], w1[k * 64 + c], s);
        y1[gi * 64 + c] = fmaxf(s, 0.f);
    }
    __syncthreads();
    for (int t = 0; t < 8; ++t) {
        int idx = t * 256 + tid;
        int gi = idx >> 5, c = idx & 31;
        float s = b2[c];
        for (int k = 0; k < 64; ++k) s = fmaf(y1[gi * 64 + k], w2[k * 32 + c], s);
        y2[gi * 32 + c] = fmaxf(s, 0.f);
    }
    __syncthreads();
    if (tid < 64) {
        float s = b3[0];
        for (int k = 0; k < 32; ++k) s = fmaf(y2[tid * 32 + k], w3[k], s);
        out[tid] = s;
    }
}

extern "C" void kernel_launch(void* const* d_in, const int* in_sizes, int n_in,
                              void* d_out, int out_size, void* d_ws, size_t ws_size,
                              hipStream_t stream)
{
    const int*   x        = (const int*)  d_in[0];
    const float* pe       = (const float*)d_in[1];
    const int*   ei       = (const int*)  d_in[2];
    const int*   eattr    = (const int*)  d_in[3];
    const float* node_emb = (const float*)d_in[5];
    const float* plw      = (const float*)d_in[6];
    const float* plb      = (const float*)d_in[7];
    const float* pe_g     = (const float*)d_in[8];
    const float* pe_b     = (const float*)d_in[9];
    const float* edge_emb = (const float*)d_in[10];
    const float* gw1      = (const float*)d_in[11];
    const float* gb1      = (const float*)d_in[12];
    const float* gw2      = (const float*)d_in[13];
    const float* gb2      = (const float*)d_in[14];
    const float* wqkv     = (const float*)d_in[15];
    const float* bqkv     = (const float*)d_in[16];
    const float* wo       = (const float*)d_in[17];
    const float* bo       = (const float*)d_in[18];
    const float* n1g      = (const float*)d_in[19];
    const float* n1b      = (const float*)d_in[20];
    const float* n2g      = (const float*)d_in[21];
    const float* n2b      = (const float*)d_in[22];
    const float* n3g      = (const float*)d_in[23];
    const float* n3b      = (const float*)d_in[24];
    const float* fw1      = (const float*)d_in[25];
    const float* fb1      = (const float*)d_in[26];
    const float* fw2      = (const float*)d_in[27];
    const float* fb2      = (const float*)d_in[28];
    const float* mw1      = (const float*)d_in[29];
    const float* mb1      = (const float*)d_in[30];
    const float* mw2      = (const float*)d_in[31];
    const float* mb2      = (const float*)d_in[32];
    const float* mw3      = (const float*)d_in[33];
    const float* mb3      = (const float*)d_in[34];

    float* wf  = (float*)d_ws;
    float* Hb  = wf;                                             // h [N,C] f32        [0,1NF)
    unsigned short* Zb16 = (unsigned short*)(wf + (size_t)NF);   // z / attn-out bf16  [1NF,1.5NF)
    float* T1  = wf + 2 * (size_t)NF;                            // t1 / t3 f32        [2NF,3NF)
    unsigned short* QKVb = (unsigned short*)(wf + 3 * (size_t)NF); // qkv bf16 [N,384] [3NF,4.5NF)
    float* T2  = wf + 3 * (size_t)NF;                            // t2 f32 (aliases dead qkv) [3NF,4NF)
    unsigned short* Y1b = (unsigned short*)(wf + 4 * (size_t)NF); // ffn hidden bf16 [N,256] [4NF,5NF)
    unsigned short* Hb16 = (unsigned short*)(wf + 5 * (size_t)NF); // h bf16 [N,C]     [5NF,5.5NF)
    int* wi     = (int*)(wf + 6 * (size_t)NF);
    int* indptr = wi;                      // N+1
    int* cnt    = wi + 32800;
    int* cnt2   = cnt + N_NODES;
    int* eid    = cnt2 + N_NODES;
    int* bsum   = eid + E_EDGES;           // 128
    int* bpre   = bsum + 128;              // 128
    float* st    = (float*)(bpre + 128);
    float* peacc = st;                     // 64
    float* bnacc = st + 64;                // 12*256
    float* pesf  = st + 64 + 12 * 256;     // 64
    float* bnsf  = pesf + 64;              // 12*256
    float* gpool = bnsf + 12 * 256;        // 64*128
    short* wT    = (short*)(gpool + 64 * 128);  // 655360 bf16 transposed weights

    const int* srcA = ei;
    const int* dstA = ei + E_EDGES;
    const int LSTR = 163840;

    hipMemsetAsync(peacc, 0, (64 + 12 * 256) * sizeof(float), stream);
    hipMemsetAsync(cnt, 0, 2 * N_NODES * sizeof(int), stream);

    wt_prep_k<<<640, 256, 0, stream>>>(gw1, gw2, wqkv, wo, fw1, fw2, wT);
    pe_stats_k<<<32, 256, 0, stream>>>(pe, peacc);
    pe_fin_k<<<1, 32, 0, stream>>>(peacc, pe_g, pe_b, pesf);
    h0_k<<<N_NODES / 2, 256, 0, stream>>>(x, pe, node_emb, plw, plb, pesf, Hb, Hb16);
    hist_k<<<E_EDGES / 256, 256, 0, stream>>>(dstA, cnt);
    bsum_k<<<128, 256, 0, stream>>>(cnt, bsum);
    bscan_k<<<1, 128, 0, stream>>>(bsum, bpre);
    indptr_k<<<128, 256, 0, stream>>>(cnt, bpre, indptr);
    scatter_k<<<E_EDGES / 256, 256, 0, stream>>>(dstA, indptr, cnt2, eid);

    for (int l = 0; l < L_LAYERS; ++l) {
        const short* gw1t  = wT + (size_t)l * LSTR;
        const short* gw2t  = wT + (size_t)l * LSTR + 16384;
        const short* wqkvt = wT + (size_t)l * LSTR + 32768;
        const short* wot   = wT + (size_t)l * LSTR + 81920;
        const short* fw1t  = wT + (size_t)l * LSTR + 98304;
        const short* fw2t  = wT + (size_t)l * LSTR + 131072;
        const float* lgb1  = gb1 + (size_t)l * 128;
        const float* lgb2  = gb2 + (size_t)l * 128;
        const float* lbqkv = bqkv + (size_t)l * 384;
        const float* lbo   = bo + (size_t)l * 128;
        const float* lfb1  = fb1 + (size_t)l * 256;
        const float* lfb2  = fb2 + (size_t)l * 128;
        float* acc1 = bnacc + (l * 3 + 0) * 256;  float* sf1v = bnsf + (l * 3 + 0) * 256;
        float* acc2 = bnacc + (l * 3 + 1) * 256;  float* sf2v = bnsf + (l * 3 + 1) * 256;
        float* acc3 = bnacc + (l * 3 + 2) * 256;  float* sf3v = bnsf + (l * 3 + 2) * 256;

        gine_gather_k<<<N_NODES / 4, 256, 0, stream>>>(Hb16, srcA, eattr, indptr, eid, edge_emb, Zb16);
        gine_mlp_k<<<256, 256, 0, stream>>>(
            Zb16, (const unsigned short*)gw1t, lgb1, (const unsigned short*)gw2t, lgb2,
            Hb, T1, acc1);
        mgemm_k<128, 384, 0, 0, false, false, true,  true ><<<dim3(3, 256), 256, 0, stream>>>(
            Hb16, nullptr, nullptr, nullptr, (const unsigned short*)wqkvt, lbqkv,
            nullptr, nullptr, nullptr, nullptr, QKVb, nullptr);
        attn_mfma_k<<<dim3(8, 4, 64), 256, 0, stream>>>(QKVb, Zb16);
        mgemm_k<128, 128, 0, 1, false, true,  false, true ><<<dim3(1, 256), 256, 0, stream>>>(
            Zb16, nullptr, nullptr, nullptr, (const unsigned short*)wot, lbo,
            Hb, nullptr, nullptr, nullptr, T2, acc2);
        bn_fin_k<<<2, 128, 0, stream>>>(acc1, n1g + l * 128, n1b + l * 128, sf1v,
                                        acc2, n2g + l * 128, n2b + l * 128, sf2v);
        mgemm_k<128, 256, 1, 0, true,  false, true,  false><<<dim3(2, 256), 256, 0, stream>>>(
            T1, T2, sf1v, sf2v, (const unsigned short*)fw1t, lfb1,
            nullptr, nullptr, nullptr, nullptr, Y1b, nullptr);
        mgemm_k<256, 128, 0, 2, false, true,  false, true ><<<dim3(1, 256), 256, 0, stream>>>(
            Y1b, nullptr, nullptr, nullptr, (const unsigned short*)fw2t, lfb2,
            T1, T2, sf1v, sf2v, T1, acc3);
        bn_fin_k<<<1, 128, 0, stream>>>(acc3, n3g + l * 128, n3b + l * 128, sf3v,
                                        nullptr, nullptr, nullptr, nullptr);
        bn_apply_k<<<NF / 1024, 256, 0, stream>>>(T1, sf3v, Hb, Hb16);
    }
    pool_k<<<B_GR, 128, 0, stream>>>(Hb, gpool);
    head_mlp_k<<<1, 256, 0, stream>>>(gpool, mw1, mb1, mw2, mb2, mw3, mb3, (float*)d_out);
}